// Round 13
// baseline (128.918 us; speedup 1.0000x reference)
//
#include <hip/hip_runtime.h>
#include <math.h>

#define NB 2
#define NL 2048
#define NK 30
#define NEF 128
#define NEIN 416
#define BM 64            // edges per block in k_edge
#define FROW 424         // fA row stride (bytes): conflict-free quarter-wave b64 reads
#define SROW 132         // staging row stride (floats)

typedef float f32x4 __attribute__((ext_vector_type(4)));
typedef unsigned long long ull;

__constant__ int c_PA[24] = {0,2,3,4,1,1,1,1,0,0,0,4,4,3,0,2,3,4,2,3,4,2,3,2};
__constant__ int c_PB[24] = {0,2,3,4,0,2,3,4,2,3,4,2,3,2,1,1,1,1,0,0,0,4,4,3};

__device__ inline ull umin64(ull a, ull b) { return a < b ? a : b; }
__device__ inline ull umax64(ull a, ull b) { return a > b ? a : b; }

// ---- kernel 0 (merged): blocks 0..15 -> atoms5 + caw4 ; blocks 16.. -> Wt fp8 ----
__global__ void k_prep(const float* __restrict__ X, const float* __restrict__ mask,
                       const float* __restrict__ eW,
                       float4* __restrict__ atoms5, float4* __restrict__ caw4,
                       unsigned char* __restrict__ Wt)
{
    int t = threadIdx.x;
    if (blockIdx.x < 16) {
        int idx = blockIdx.x * 256 + t;           // 16*256 = 4096 = NB*NL exactly
        const float* x = X + (size_t)idx * 12;
        float N[3], Ca[3], C[3], O[3], bv[3], cv[3], av[3];
#pragma unroll
        for (int d = 0; d < 3; d++) { N[d] = x[d]; Ca[d] = x[3+d]; C[d] = x[6+d]; O[d] = x[9+d]; }
#pragma unroll
        for (int d = 0; d < 3; d++) { bv[d] = Ca[d] - N[d]; cv[d] = C[d] - Ca[d]; }
        av[0] = bv[1]*cv[2] - bv[2]*cv[1];
        av[1] = bv[2]*cv[0] - bv[0]*cv[2];
        av[2] = bv[0]*cv[1] - bv[1]*cv[0];
        float4* o = atoms5 + (size_t)idx * 5;
        o[0] = make_float4(N[0], N[1], N[2], 0.f);
        o[1] = make_float4(Ca[0], Ca[1], Ca[2], 0.f);
        o[2] = make_float4(C[0], C[1], C[2], 0.f);
        o[3] = make_float4(O[0], O[1], O[2], 0.f);
        float cb0 = -0.58273431f*av[0] + 0.56802827f*bv[0] - 0.54067466f*cv[0] + Ca[0];
        float cb1 = -0.58273431f*av[1] + 0.56802827f*bv[1] - 0.54067466f*cv[1] + Ca[1];
        float cb2 = -0.58273431f*av[2] + 0.56802827f*bv[2] - 0.54067466f*cv[2] + Ca[2];
        o[4] = make_float4(cb0, cb1, cb2, 0.f);
        caw4[idx] = make_float4(Ca[0], Ca[1], Ca[2], mask[idx]);
    } else {
        int idx = (blockIdx.x - 16) * 256 + t;    // 104*256 = 26624 = NEF*NEIN/2
        if (idx >= NEF * (NEIN / 2)) return;
        int c  = idx / (NEIN / 2);
        int k2 = idx - c * (NEIN / 2);
        float a = eW[(size_t)(2 * k2) * NEF + c];
        float b = eW[(size_t)(2 * k2 + 1) * NEF + c];
        int r = __builtin_amdgcn_cvt_pk_fp8_f32(a, b, 0, false);
        *(unsigned short*)&Wt[(size_t)c * NEIN + 2 * k2] = (unsigned short)(r & 0xffff);
    }
}

// ---- kernel 1: exact top-30, one WAVE per row, streaming 4-slot min-list ----
__global__ __launch_bounds__(256, 4) void k_topk(const float4* __restrict__ caw4,
                                                 float* __restrict__ dnb,
                                                 int*   __restrict__ eidx,
                                                 float* __restrict__ eidx_f)
{
    __shared__ float4 ca[NL];
    int t = threadIdx.x;
    int base = blockIdx.x << 2;          // 4 rows per block (one per wave)
    int b = base >> 11;
    const float4* src = caw4 + (size_t)b * NL;
#pragma unroll
    for (int r = 0; r < NL/256; r++) ca[t + r*256] = src[t + r*256];
    __syncthreads();

    int w = t >> 6, lane = t & 63;
    int row = base + w;
    int i = row & (NL - 1);
    float4 ci = ca[i];
    float mi = ci.w;

    float df[32];
    unsigned mflags = 0;
    float lmax = 0.0f;
#pragma unroll
    for (int r = 0; r < 32; r++) {
        float4 cj = ca[r*64 + lane];
        float dx = __fsub_rn(ci.x, cj.x);
        float dy = __fsub_rn(ci.y, cj.y);
        float dz = __fsub_rn(ci.z, cj.z);
        float s  = __fadd_rn(__fadd_rn(__fmul_rn(dx,dx), __fmul_rn(dy,dy)), __fmul_rn(dz,dz));
        s = __fadd_rn(s, 1e-6f);
        float m2 = __fmul_rn(mi, cj.w);   // binary mask: 0 or 1
        float d  = __fmul_rn(m2, __fsqrt_rn(s));
        df[r] = d;
        lmax = fmaxf(lmax, d);
        mflags |= (m2 != 0.0f) ? (1u << r) : 0u;
    }
#pragma unroll
    for (int off = 32; off; off >>= 1) lmax = fmaxf(lmax, __shfl_xor(lmax, off));
    unsigned rmb = __float_as_uint(lmax);

    const ull INF = ~0ULL;
    ull m0 = INF, m1 = INF, m2k = INF, m3 = INF;
#pragma unroll
    for (int r = 0; r < 32; r++) {
        unsigned hi = ((mflags >> r) & 1u) ? __float_as_uint(df[r]) : rmb;
        ull key = ((ull)hi << 32) | (unsigned)(r*64 + lane);
        ull a0 = umin64(key, m0); ull k1 = umax64(key, m0); m0 = a0;
        ull a1 = umin64(k1, m1);  ull k2 = umax64(k1, m1);  m1 = a1;
        ull a2 = umin64(k2, m2k); ull k3 = umax64(k2, m2k); m2k = a2;
        m3 = umin64(k3, m3);
    }

    int c = 0;
    ull mykey = 0;
    for (int sel = 0; sel < NK; sel++) {
        ull g = m0;
#pragma unroll
        for (int off = 32; off; off >>= 1) {
            ull o = __shfl_xor(g, off);
            g = o < g ? o : g;
        }
        if (m0 == g) {
            m0 = m1; m1 = m2k; m2k = m3; m3 = INF;
            c++;
            if (m0 == INF && c < 32) {
#pragma unroll
                for (int r = 0; r < 32; r++) {
                    unsigned hi = ((mflags >> r) & 1u) ? __float_as_uint(df[r]) : rmb;
                    ull key = ((ull)hi << 32) | (unsigned)(r*64 + lane);
                    if (key > g) {
                        ull a0 = umin64(key, m0); ull k1 = umax64(key, m0); m0 = a0;
                        ull a1 = umin64(k1, m1);  ull k2 = umax64(k1, m1);  m1 = a1;
                        ull a2 = umin64(k2, m2k); ull k3 = umax64(k2, m2k); m2k = a2;
                        m3 = umin64(k3, m3);
                    }
                }
            }
        }
        mykey = (lane == sel) ? g : mykey;
    }
    if (lane < NK) {
        int g = row * NK + lane;
        int j = (int)(mykey & 0xffffffffULL);
        dnb[g]    = __uint_as_float((unsigned)(mykey >> 32));
        eidx[g]   = j;
        eidx_f[g] = (float)j;
    }
}

// ------- kernel 2: features(fp8) + fp8 MFMA GEMM + LayerNorm, 512 thr / 8 waves -------
// 5 barriers total; single staging pass; NT stream-out LAST with no trailing
// barrier (r12's per-half sync forced vmcnt(0) on NT stores -> block-wide HBM
// round-trip stalls). LN: butterfly-exchange reduce (30 DS ops vs 128).
__global__ __launch_bounds__(512, 4) void k_edge(const float4* __restrict__ atoms5,
                                              const int*   __restrict__ eidx,
                                              const float* __restrict__ dnb,
                                              const int*   __restrict__ ridx,
                                              const int*   __restrict__ chl,
                                              const float* __restrict__ posW,
                                              const float* __restrict__ posb,
                                              const unsigned char* __restrict__ Wt,
                                              const float* __restrict__ lns,
                                              const float* __restrict__ lno,
                                              float* __restrict__ Eout)
{
    // LDS union: phase A: fA[64][424] = 27136 B
    //            phase B: red_s[8*64] + red_q[8*64] + red2[64*2] + staging[64*132]
    //                     = (512+512+128+8448)*4 = 38400 B
    __shared__ __align__(16) unsigned char smem[38400];
    unsigned char (*fA)[FROW] = (unsigned char (*)[FROW])smem;
    int t = threadIdx.x;
    int base = blockIdx.x * BM;

    int w    = t >> 6;
    int lane = t & 63;
    int l16  = lane & 15;
    int lg   = lane >> 4;
    int g8   = lg * 8;
    int ncol = w * 16;

    // ---- B preload FIRST: 13 x 8B independent loads; latency hides under phase 1.
    const unsigned char* wtb = Wt + (size_t)(ncol + l16) * NEIN + g8;
    long bfr[13];
#pragma unroll
    for (int kt = 0; kt < 13; kt++)
        bfr[kt] = *(const long*)(wtb + kt * 32);

    // ---- phase 1: features, p-split, fp8-packed.
    {
        int e = t >> 3;
        int q = t & 7;
        int g = base + e;
        int b = g / (NL * NK);
        int rem = g - b * (NL * NK);
        int i = rem / NK;
        int gi = b * NL + i;
        int j = eidx[g];
        int gj = b * NL + j;

        int off = ridx[gi] - ridx[gj];
        int ec  = (chl[gi] == chl[gj]) ? 1 : 0;
        int dp  = min(max(off + 32, 0), 64);
        dp = ec ? dp : 65;
        {
            float p0 = posW[dp * 16 + 2*q]     + posb[2*q];
            float p1 = posW[dp * 16 + 2*q + 1] + posb[2*q + 1];
            int r = __builtin_amdgcn_cvt_pk_fp8_f32(p0, p1, 0, false);
            *(unsigned short*)&fA[e][q * 2] = (unsigned short)(r & 0xffff);
        }

        const float4* A4 = atoms5 + (size_t)gi * 5;
        const float4* B4 = atoms5 + (size_t)gj * 5;

        auto body = [&](int p) {
            float D;
            if (p == 0) {
                D = dnb[g];
            } else {
                float4 a  = A4[c_PA[p - 1]];
                float4 bb = B4[c_PB[p - 1]];
                float dx = a.x - bb.x, dy = a.y - bb.y, dz = a.z - bb.z;
                D = sqrtf(dx*dx + dy*dy + dz*dz + 1e-6f);
            }
            float tD = D * 0.8f;                  // prescale: z = tD - mu*0.8
            int wds[4];
#pragma unroll
            for (int gq = 0; gq < 4; gq++) {
                float v[4];
#pragma unroll
                for (int u = 0; u < 4; u++) {
                    int s = gq * 4 + u;
                    float z = tD - (1.6f + (float)s * 1.06666667f);
                    v[u] = __expf(-(z * z));
                }
                int r = __builtin_amdgcn_cvt_pk_fp8_f32(v[0], v[1], 0, false);
                r = __builtin_amdgcn_cvt_pk_fp8_f32(v[2], v[3], r, true);
                wds[gq] = r;
            }
            long lo = ((long)(unsigned)wds[1] << 32) | (unsigned)wds[0];
            long hi = ((long)(unsigned)wds[3] << 32) | (unsigned)wds[2];
            *(long*)&fA[e][16 + p * 16]     = lo;
            *(long*)&fA[e][16 + p * 16 + 8] = hi;
        };

#pragma unroll
        for (int pp = 0; pp < 3; pp++) body(q + pp * 8);
        if (q == 0) body(24);
    }

    __syncthreads();                               // B1

    // ---- phase 2: GEMM. 52 MFMA + 52 conflict-free ds_read_b64 per wave.
    f32x4 acc[4];
#pragma unroll
    for (int mt = 0; mt < 4; mt++) acc[mt] = (f32x4){0.f, 0.f, 0.f, 0.f};

#pragma unroll
    for (int kt = 0; kt < 13; kt++) {
#pragma unroll
        for (int mt = 0; mt < 4; mt++) {
            long a = *(const long*)(&fA[mt * 16 + l16][kt * 32 + g8]);
            acc[mt] = __builtin_amdgcn_mfma_f32_16x16x32_fp8_fp8(a, bfr[kt], acc[mt], 0, 0, 0);
        }
    }

    // ---- phase 3: LN partials via butterfly-exchange (each lane ends with ONE row).
    float v[16], q2[16];
#pragma unroll
    for (int mt = 0; mt < 4; mt++)
#pragma unroll
        for (int r = 0; r < 4; r++) {
            float x = acc[mt][r];
            v[mt*4 + r]  = x;
            q2[mt*4 + r] = x * x;
        }
#pragma unroll
    for (int s = 1; s <= 8; s <<= 1) {
        int half = 8 / s;                          // 8,4,2,1
        int bsel = (l16 & s) ? 1 : 0;
#pragma unroll 8
        for (int i = 0; i < half; i++) {
            float ks = v[i + bsel*half],  ss = v[i + (1-bsel)*half];
            float kq = q2[i + bsel*half], sq = q2[i + (1-bsel)*half];
            v[i]  = ks + __shfl_xor(ss, s);
            q2[i] = kq + __shfl_xor(sq, s);
        }
    }
    // lane's row: istar = bitrev4(l16); row = (istar>>2)*16 + lg*4 + (istar&3)
    int istar = ((l16&1)<<3) | ((l16&2)<<1) | ((l16&4)>>1) | ((l16&8)>>3);
    int myrow = (istar >> 2) * 16 + lg * 4 + (istar & 3);

    __syncthreads();                               // B2: all fA reads done, reuse LDS
    float* red_s   = (float*)smem;                 // [8][64]
    float* red_q   = red_s + 512;                  // [8][64]
    float* red2    = red_q + 512;                  // [64][2]
    float* staging = red2 + 128;                   // [64][SROW]
    red_s[w * 64 + myrow] = v[0];
    red_q[w * 64 + myrow] = q2[0];
    __syncthreads();                               // B3

    if (t < 64) {
        float ts = 0.f, tq = 0.f;
#pragma unroll
        for (int u = 0; u < 8; u++) {
            ts += red_s[u * 64 + t];
            tq += red_q[u * 64 + t];
        }
        float mu  = ts * (1.0f / 128.0f);
        float var = tq * (1.0f / 128.0f) - mu * mu;
        red2[t * 2 + 0] = mu;
        red2[t * 2 + 1] = 1.0f / sqrtf(var + 1e-5f);
    }
    __syncthreads();                               // B4

    // ---- phase 4: single staging pass (all 64 rows), then NT stream-out LAST.
    float sc = lns[ncol + l16];
    float of = lno[ncol + l16];
#pragma unroll
    for (int mt = 0; mt < 4; mt++)
#pragma unroll
        for (int r = 0; r < 4; r++) {
            int row = mt * 16 + lg * 4 + r;
            float mu = red2[row * 2 + 0];
            float rs = red2[row * 2 + 1];
            staging[row * SROW + ncol + l16] =
                sc * ((acc[mt][r] - mu) * rs) + of;
        }
    __syncthreads();                               // B5

    f32x4* Eout4 = (f32x4*)Eout;
#pragma unroll
    for (int u = 0; u < 4; u++) {
        int idx  = u * 512 + t;                    // 0..2047
        int lrow = idx >> 5;
        int c4   = idx & 31;
        f32x4 val = *(f32x4*)&staging[lrow * SROW + c4 * 4];
        __builtin_nontemporal_store(val, &Eout4[(size_t)(base + lrow) * 32 + c4]);
    }
    // no trailing barrier: stores drain as waves retire
}

extern "C" void kernel_launch(void* const* d_in, const int* in_sizes, int n_in,
                              void* d_out, int out_size, void* d_ws, size_t ws_size,
                              hipStream_t stream)
{
    const float* X    = (const float*)d_in[0];
    const float* mask = (const float*)d_in[1];
    const int*   ridx = (const int*)d_in[2];
    const int*   chl  = (const int*)d_in[3];
    const float* posW = (const float*)d_in[4];
    const float* posb = (const float*)d_in[5];
    const float* eW   = (const float*)d_in[6];
    const float* lns  = (const float*)d_in[7];
    const float* lno  = (const float*)d_in[8];

    float* Eout   = (float*)d_out;                                  // B*L*K*128
    float* eidx_f = Eout + (size_t)NB * NL * NK * NEF;              // B*L*K (as float)

    char* ws = (char*)d_ws;
    float4*        atoms5 = (float4*)ws;                            // 327680 B
    float*         dnb    = (float*)(ws + 327680);                  // 491520 B
    int*           eidx   = (int*)(ws + 819200);                    // 491520 B
    unsigned char* Wt     = (unsigned char*)(ws + 1310720);         // 53248 B
    float4*        caw4   = (float4*)(ws + 1363968);                // 65536 B

    k_prep<<<16 + (NEF * (NEIN/2) + 255) / 256, 256, 0, stream>>>(X, mask, eW, atoms5, caw4, Wt);
    k_topk<<<(NB * NL) / 4, 256, 0, stream>>>(caw4, dnb, eidx, eidx_f);
    k_edge<<<(NB * NL * NK) / BM, 512, 0, stream>>>(atoms5, eidx, dnb, ridx, chl,
                                                    posW, posb, Wt, lns, lno, Eout);
}

// Round 14
// 103.871 us; speedup vs baseline: 1.2411x; 1.2411x over previous
//
#include <hip/hip_runtime.h>
#include <math.h>

#define NB 2
#define NL 2048
#define NK 30
#define NEF 128
#define NEIN 416
#define BM 64            // edges per tile in k_edge
#define TILES 4          // tiles per block -> grid 480
#define FROW 424         // fA row stride (bytes): conflict-free quarter-wave b64 reads

typedef float f32x4 __attribute__((ext_vector_type(4)));
typedef unsigned long long ull;

__constant__ int c_PA[24] = {0,2,3,4,1,1,1,1,0,0,0,4,4,3,0,2,3,4,2,3,4,2,3,2};
__constant__ int c_PB[24] = {0,2,3,4,0,2,3,4,2,3,4,2,3,2,1,1,1,1,0,0,0,4,4,3};

__device__ inline ull umin64(ull a, ull b) { return a < b ? a : b; }
__device__ inline ull umax64(ull a, ull b) { return a > b ? a : b; }

// ---- kernel 0 (merged): blocks 0..15 -> atoms5 + caw4 ; blocks 16.. -> Wt fp8 ----
__global__ void k_prep(const float* __restrict__ X, const float* __restrict__ mask,
                       const float* __restrict__ eW,
                       float4* __restrict__ atoms5, float4* __restrict__ caw4,
                       unsigned char* __restrict__ Wt)
{
    int t = threadIdx.x;
    if (blockIdx.x < 16) {
        int idx = blockIdx.x * 256 + t;           // 16*256 = 4096 = NB*NL exactly
        const float* x = X + (size_t)idx * 12;
        float N[3], Ca[3], C[3], O[3], bv[3], cv[3], av[3];
#pragma unroll
        for (int d = 0; d < 3; d++) { N[d] = x[d]; Ca[d] = x[3+d]; C[d] = x[6+d]; O[d] = x[9+d]; }
#pragma unroll
        for (int d = 0; d < 3; d++) { bv[d] = Ca[d] - N[d]; cv[d] = C[d] - Ca[d]; }
        av[0] = bv[1]*cv[2] - bv[2]*cv[1];
        av[1] = bv[2]*cv[0] - bv[0]*cv[2];
        av[2] = bv[0]*cv[1] - bv[1]*cv[0];
        float4* o = atoms5 + (size_t)idx * 5;
        o[0] = make_float4(N[0], N[1], N[2], 0.f);
        o[1] = make_float4(Ca[0], Ca[1], Ca[2], 0.f);
        o[2] = make_float4(C[0], C[1], C[2], 0.f);
        o[3] = make_float4(O[0], O[1], O[2], 0.f);
        float cb0 = -0.58273431f*av[0] + 0.56802827f*bv[0] - 0.54067466f*cv[0] + Ca[0];
        float cb1 = -0.58273431f*av[1] + 0.56802827f*bv[1] - 0.54067466f*cv[1] + Ca[1];
        float cb2 = -0.58273431f*av[2] + 0.56802827f*bv[2] - 0.54067466f*cv[2] + Ca[2];
        o[4] = make_float4(cb0, cb1, cb2, 0.f);
        caw4[idx] = make_float4(Ca[0], Ca[1], Ca[2], mask[idx]);
    } else {
        int idx = (blockIdx.x - 16) * 256 + t;    // 104*256 = 26624 = NEF*NEIN/2
        if (idx >= NEF * (NEIN / 2)) return;
        int c  = idx / (NEIN / 2);
        int k2 = idx - c * (NEIN / 2);
        float a = eW[(size_t)(2 * k2) * NEF + c];
        float b = eW[(size_t)(2 * k2 + 1) * NEF + c];
        int r = __builtin_amdgcn_cvt_pk_fp8_f32(a, b, 0, false);
        *(unsigned short*)&Wt[(size_t)c * NEIN + 2 * k2] = (unsigned short)(r & 0xffff);
    }
}

// ---- kernel 1: exact top-30, one WAVE per row, streaming 4-slot min-list ----
__global__ __launch_bounds__(256, 4) void k_topk(const float4* __restrict__ caw4,
                                                 float* __restrict__ dnb,
                                                 int*   __restrict__ eidx,
                                                 float* __restrict__ eidx_f)
{
    __shared__ float4 ca[NL];
    int t = threadIdx.x;
    int base = blockIdx.x << 2;          // 4 rows per block (one per wave)
    int b = base >> 11;
    const float4* src = caw4 + (size_t)b * NL;
#pragma unroll
    for (int r = 0; r < NL/256; r++) ca[t + r*256] = src[t + r*256];
    __syncthreads();

    int w = t >> 6, lane = t & 63;
    int row = base + w;
    int i = row & (NL - 1);
    float4 ci = ca[i];
    float mi = ci.w;

    float df[32];
    unsigned mflags = 0;
    float lmax = 0.0f;
#pragma unroll
    for (int r = 0; r < 32; r++) {
        float4 cj = ca[r*64 + lane];
        float dx = __fsub_rn(ci.x, cj.x);
        float dy = __fsub_rn(ci.y, cj.y);
        float dz = __fsub_rn(ci.z, cj.z);
        float s  = __fadd_rn(__fadd_rn(__fmul_rn(dx,dx), __fmul_rn(dy,dy)), __fmul_rn(dz,dz));
        s = __fadd_rn(s, 1e-6f);
        float m2 = __fmul_rn(mi, cj.w);   // binary mask: 0 or 1
        float d  = __fmul_rn(m2, __fsqrt_rn(s));
        df[r] = d;
        lmax = fmaxf(lmax, d);
        mflags |= (m2 != 0.0f) ? (1u << r) : 0u;
    }
#pragma unroll
    for (int off = 32; off; off >>= 1) lmax = fmaxf(lmax, __shfl_xor(lmax, off));
    unsigned rmb = __float_as_uint(lmax);

    const ull INF = ~0ULL;
    ull m0 = INF, m1 = INF, m2k = INF, m3 = INF;
#pragma unroll
    for (int r = 0; r < 32; r++) {
        unsigned hi = ((mflags >> r) & 1u) ? __float_as_uint(df[r]) : rmb;
        ull key = ((ull)hi << 32) | (unsigned)(r*64 + lane);
        ull a0 = umin64(key, m0); ull k1 = umax64(key, m0); m0 = a0;
        ull a1 = umin64(k1, m1);  ull k2 = umax64(k1, m1);  m1 = a1;
        ull a2 = umin64(k2, m2k); ull k3 = umax64(k2, m2k); m2k = a2;
        m3 = umin64(k3, m3);
    }

    int c = 0;
    ull mykey = 0;
    for (int sel = 0; sel < NK; sel++) {
        ull g = m0;
#pragma unroll
        for (int off = 32; off; off >>= 1) {
            ull o = __shfl_xor(g, off);
            g = o < g ? o : g;
        }
        if (m0 == g) {
            m0 = m1; m1 = m2k; m2k = m3; m3 = INF;
            c++;
            if (m0 == INF && c < 32) {
#pragma unroll
                for (int r = 0; r < 32; r++) {
                    unsigned hi = ((mflags >> r) & 1u) ? __float_as_uint(df[r]) : rmb;
                    ull key = ((ull)hi << 32) | (unsigned)(r*64 + lane);
                    if (key > g) {
                        ull a0 = umin64(key, m0); ull k1 = umax64(key, m0); m0 = a0;
                        ull a1 = umin64(k1, m1);  ull k2 = umax64(k1, m1);  m1 = a1;
                        ull a2 = umin64(k2, m2k); ull k3 = umax64(k2, m2k); m2k = a2;
                        m3 = umin64(k3, m3);
                    }
                }
            }
        }
        mykey = (lane == sel) ? g : mykey;
    }
    if (lane < NK) {
        int g = row * NK + lane;
        int j = (int)(mykey & 0xffffffffULL);
        dnb[g]    = __uint_as_float((unsigned)(mykey >> 32));
        eidx[g]   = j;
        eidx_f[g] = (float)j;
    }
}

// ------- kernel 2: 4 tiles of 64 edges per block (grid 480), pipelined -------
// Per tile: phase1 -> B1 -> GEMM -> LN shfl -> red write -> B2 -> red2 -> B3 ->
// direct scattered stores (NO trailing barrier: drain hides under next tile's
// exp-heavy phase1). bfr preloaded ONCE per block (cols fixed across tiles).
__global__ __launch_bounds__(512, 4) void k_edge(const float4* __restrict__ atoms5,
                                              const int*   __restrict__ eidx,
                                              const float* __restrict__ dnb,
                                              const int*   __restrict__ ridx,
                                              const int*   __restrict__ chl,
                                              const float* __restrict__ posW,
                                              const float* __restrict__ posb,
                                              const unsigned char* __restrict__ Wt,
                                              const float* __restrict__ lns,
                                              const float* __restrict__ lno,
                                              float* __restrict__ Eout)
{
    __shared__ __align__(16) unsigned char fA[BM][FROW];   // 27136 B
    __shared__ float red[BM * 8 * 2];                       // 4096 B
    __shared__ float red2[BM * 2];                          // 512 B
    int t = threadIdx.x;

    int w    = t >> 6;
    int lane = t & 63;
    int l16  = lane & 15;
    int lg   = lane >> 4;
    int g8   = lg * 8;
    int ncol = w * 16;

    // ---- B preload ONCE: 13 x 8B; cols identical for all tiles of this block.
    const unsigned char* wtb = Wt + (size_t)(ncol + l16) * NEIN + g8;
    long bfr[13];
#pragma unroll
    for (int kt = 0; kt < 13; kt++)
        bfr[kt] = *(const long*)(wtb + kt * 32);

    float sc = lns[ncol + l16];
    float of = lno[ncol + l16];

    for (int tt = 0; tt < TILES; tt++) {
        int base = blockIdx.x * (BM * TILES) + tt * BM;

        // ---- phase 1: features, p-split, fp8-packed (overlaps prev tile's store drain).
        {
            int e = t >> 3;
            int q = t & 7;
            int g = base + e;
            int b = g / (NL * NK);
            int rem = g - b * (NL * NK);
            int i = rem / NK;
            int gi = b * NL + i;
            int j = eidx[g];
            int gj = b * NL + j;

            int off = ridx[gi] - ridx[gj];
            int ec  = (chl[gi] == chl[gj]) ? 1 : 0;
            int dp  = min(max(off + 32, 0), 64);
            dp = ec ? dp : 65;
            {
                float p0 = posW[dp * 16 + 2*q]     + posb[2*q];
                float p1 = posW[dp * 16 + 2*q + 1] + posb[2*q + 1];
                int r = __builtin_amdgcn_cvt_pk_fp8_f32(p0, p1, 0, false);
                *(unsigned short*)&fA[e][q * 2] = (unsigned short)(r & 0xffff);
            }

            const float4* A4 = atoms5 + (size_t)gi * 5;
            const float4* B4 = atoms5 + (size_t)gj * 5;

            auto body = [&](int p) {
                float D;
                if (p == 0) {
                    D = dnb[g];
                } else {
                    float4 a  = A4[c_PA[p - 1]];
                    float4 bb = B4[c_PB[p - 1]];
                    float dx = a.x - bb.x, dy = a.y - bb.y, dz = a.z - bb.z;
                    D = sqrtf(dx*dx + dy*dy + dz*dz + 1e-6f);
                }
                float tD = D * 0.8f;                  // prescale: z = tD - mu*0.8
                int wds[4];
#pragma unroll
                for (int gq = 0; gq < 4; gq++) {
                    float v[4];
#pragma unroll
                    for (int u = 0; u < 4; u++) {
                        int s = gq * 4 + u;
                        float z = tD - (1.6f + (float)s * 1.06666667f);
                        v[u] = __expf(-(z * z));
                    }
                    int r = __builtin_amdgcn_cvt_pk_fp8_f32(v[0], v[1], 0, false);
                    r = __builtin_amdgcn_cvt_pk_fp8_f32(v[2], v[3], r, true);
                    wds[gq] = r;
                }
                long lo = ((long)(unsigned)wds[1] << 32) | (unsigned)wds[0];
                long hi = ((long)(unsigned)wds[3] << 32) | (unsigned)wds[2];
                *(long*)&fA[e][16 + p * 16]     = lo;
                *(long*)&fA[e][16 + p * 16 + 8] = hi;
            };

#pragma unroll
            for (int pp = 0; pp < 3; pp++) body(q + pp * 8);
            if (q == 0) body(24);
        }

        __syncthreads();                               // B1

        // ---- phase 2: GEMM. 52 MFMA + 52 conflict-free ds_read_b64 per wave.
        f32x4 acc[4];
#pragma unroll
        for (int mt = 0; mt < 4; mt++) acc[mt] = (f32x4){0.f, 0.f, 0.f, 0.f};

#pragma unroll
        for (int kt = 0; kt < 13; kt++) {
#pragma unroll
            for (int mt = 0; mt < 4; mt++) {
                long a = *(const long*)(&fA[mt * 16 + l16][kt * 32 + g8]);
                acc[mt] = __builtin_amdgcn_mfma_f32_16x16x32_fp8_fp8(a, bfr[kt], acc[mt], 0, 0, 0);
            }
        }

        // ---- phase 3: LN stats, in-wave shfl reduce (r12-proven).
        float sum[4][4], ssq[4][4];
#pragma unroll
        for (int mt = 0; mt < 4; mt++)
#pragma unroll
            for (int r = 0; r < 4; r++) {
                float v = acc[mt][r];
                sum[mt][r] = v;
                ssq[mt][r] = v * v;
            }
#pragma unroll
        for (int off = 1; off < 16; off <<= 1)
#pragma unroll
            for (int mt = 0; mt < 4; mt++)
#pragma unroll
                for (int r = 0; r < 4; r++) {
                    sum[mt][r] += __shfl_xor(sum[mt][r], off);
                    ssq[mt][r] += __shfl_xor(ssq[mt][r], off);
                }

        if (l16 == 0) {
#pragma unroll
            for (int mt = 0; mt < 4; mt++)
#pragma unroll
                for (int r = 0; r < 4; r++) {
                    int row = mt * 16 + lg * 4 + r;
                    red[(row * 8 + w) * 2 + 0] = sum[mt][r];
                    red[(row * 8 + w) * 2 + 1] = ssq[mt][r];
                }
        }
        __syncthreads();                               // B2

        if (t < 64) {
            float ts = 0.f, tq = 0.f;
#pragma unroll
            for (int u = 0; u < 8; u++) {
                ts += red[(t * 8 + u) * 2 + 0];
                tq += red[(t * 8 + u) * 2 + 1];
            }
            float mu  = ts * (1.0f / 128.0f);
            float var = tq * (1.0f / 128.0f) - mu * mu;
            red2[t * 2 + 0] = mu;
            red2[t * 2 + 1] = 1.0f / sqrtf(var + 1e-5f);
        }
        __syncthreads();                               // B3

        // ---- phase 4: direct scattered stores (r6-proven 1.0x WRITE), no barrier.
#pragma unroll
        for (int mt = 0; mt < 4; mt++)
#pragma unroll
            for (int r = 0; r < 4; r++) {
                int row = mt * 16 + lg * 4 + r;
                float mu = red2[row * 2 + 0];
                float rs = red2[row * 2 + 1];
                Eout[(size_t)(base + row) * NEF + ncol + l16] =
                    sc * ((acc[mt][r] - mu) * rs) + of;
            }
        // store drain overlaps next tile's phase 1 (no barrier until B1)
    }
}

extern "C" void kernel_launch(void* const* d_in, const int* in_sizes, int n_in,
                              void* d_out, int out_size, void* d_ws, size_t ws_size,
                              hipStream_t stream)
{
    const float* X    = (const float*)d_in[0];
    const float* mask = (const float*)d_in[1];
    const int*   ridx = (const int*)d_in[2];
    const int*   chl  = (const int*)d_in[3];
    const float* posW = (const float*)d_in[4];
    const float* posb = (const float*)d_in[5];
    const float* eW   = (const float*)d_in[6];
    const float* lns  = (const float*)d_in[7];
    const float* lno  = (const float*)d_in[8];

    float* Eout   = (float*)d_out;                                  // B*L*K*128
    float* eidx_f = Eout + (size_t)NB * NL * NK * NEF;              // B*L*K (as float)

    char* ws = (char*)d_ws;
    float4*        atoms5 = (float4*)ws;                            // 327680 B
    float*         dnb    = (float*)(ws + 327680);                  // 491520 B
    int*           eidx   = (int*)(ws + 819200);                    // 491520 B
    unsigned char* Wt     = (unsigned char*)(ws + 1310720);         // 53248 B
    float4*        caw4   = (float4*)(ws + 1363968);                // 65536 B

    k_prep<<<16 + (NEF * (NEIN/2) + 255) / 256, 256, 0, stream>>>(X, mask, eW, atoms5, caw4, Wt);
    k_topk<<<(NB * NL) / 4, 256, 0, stream>>>(caw4, dnb, eidx, eidx_f);
    k_edge<<<(NB * NL * NK) / (BM * TILES), 512, 0, stream>>>(atoms5, eidx, dnb, ridx, chl,
                                                              posW, posb, Wt, lns, lno, Eout);
}

// Round 15
// 83.728 us; speedup vs baseline: 1.5397x; 1.2406x over previous
//
#include <hip/hip_runtime.h>
#include <math.h>

#define NB 2
#define NL 2048
#define NK 30
#define NEF 128
#define NEIN 416
#define BM 64            // edges per block in k_edge
#define FROW 424         // fA row stride (bytes): conflict-free quarter-wave b64 reads
#define SROW 132         // staging row stride (floats)

typedef float f32x4 __attribute__((ext_vector_type(4)));
typedef unsigned long long ull;

__constant__ int c_PA[24] = {0,2,3,4,1,1,1,1,0,0,0,4,4,3,0,2,3,4,2,3,4,2,3,2};
__constant__ int c_PB[24] = {0,2,3,4,0,2,3,4,2,3,4,2,3,2,1,1,1,1,0,0,0,4,4,3};

__device__ inline ull umin64(ull a, ull b) { return a < b ? a : b; }
__device__ inline ull umax64(ull a, ull b) { return a > b ? a : b; }

// 16-lane sum via DPP (VALU only, no DS pipe). Bit-identical to shfl_xor 1,2,4,8:
// after xor1+xor2 every lane of a quad holds the quad-sum, so half_mirror/mirror
// add the same values xor4/xor8 would.
template<int CTRL>
__device__ inline float dpp_add(float v) {
    int x = __builtin_amdgcn_update_dpp(0, __float_as_int(v), CTRL, 0xF, 0xF, true);
    return v + __int_as_float(x);
}
__device__ inline float row16_sum(float v) {
    v = dpp_add<0xB1>(v);    // quad_perm [1,0,3,2]  == xor1
    v = dpp_add<0x4E>(v);    // quad_perm [2,3,0,1]  == xor2
    v = dpp_add<0x141>(v);   // row_half_mirror      == xor4 (post quad-uniform)
    v = dpp_add<0x140>(v);   // row_mirror           == xor8
    return v;
}

// ---- kernel 0 (merged): blocks 0..15 -> atoms5 + caw4 ; blocks 16.. -> Wt fp8 ----
__global__ void k_prep(const float* __restrict__ X, const float* __restrict__ mask,
                       const float* __restrict__ eW,
                       float4* __restrict__ atoms5, float4* __restrict__ caw4,
                       unsigned char* __restrict__ Wt)
{
    int t = threadIdx.x;
    if (blockIdx.x < 16) {
        int idx = blockIdx.x * 256 + t;           // 16*256 = 4096 = NB*NL exactly
        const float* x = X + (size_t)idx * 12;
        float N[3], Ca[3], C[3], O[3], bv[3], cv[3], av[3];
#pragma unroll
        for (int d = 0; d < 3; d++) { N[d] = x[d]; Ca[d] = x[3+d]; C[d] = x[6+d]; O[d] = x[9+d]; }
#pragma unroll
        for (int d = 0; d < 3; d++) { bv[d] = Ca[d] - N[d]; cv[d] = C[d] - Ca[d]; }
        av[0] = bv[1]*cv[2] - bv[2]*cv[1];
        av[1] = bv[2]*cv[0] - bv[0]*cv[2];
        av[2] = bv[0]*cv[1] - bv[1]*cv[0];
        float4* o = atoms5 + (size_t)idx * 5;
        o[0] = make_float4(N[0], N[1], N[2], 0.f);
        o[1] = make_float4(Ca[0], Ca[1], Ca[2], 0.f);
        o[2] = make_float4(C[0], C[1], C[2], 0.f);
        o[3] = make_float4(O[0], O[1], O[2], 0.f);
        float cb0 = -0.58273431f*av[0] + 0.56802827f*bv[0] - 0.54067466f*cv[0] + Ca[0];
        float cb1 = -0.58273431f*av[1] + 0.56802827f*bv[1] - 0.54067466f*cv[1] + Ca[1];
        float cb2 = -0.58273431f*av[2] + 0.56802827f*bv[2] - 0.54067466f*cv[2] + Ca[2];
        o[4] = make_float4(cb0, cb1, cb2, 0.f);
        caw4[idx] = make_float4(Ca[0], Ca[1], Ca[2], mask[idx]);
    } else {
        int idx = (blockIdx.x - 16) * 256 + t;    // 104*256 = 26624 = NEF*NEIN/2
        if (idx >= NEF * (NEIN / 2)) return;
        int c  = idx / (NEIN / 2);
        int k2 = idx - c * (NEIN / 2);
        float a = eW[(size_t)(2 * k2) * NEF + c];
        float b = eW[(size_t)(2 * k2 + 1) * NEF + c];
        int r = __builtin_amdgcn_cvt_pk_fp8_f32(a, b, 0, false);
        *(unsigned short*)&Wt[(size_t)c * NEIN + 2 * k2] = (unsigned short)(r & 0xffff);
    }
}

// ---- kernel 1: exact top-30, one WAVE per row, streaming 4-slot min-list ----
__global__ __launch_bounds__(256, 4) void k_topk(const float4* __restrict__ caw4,
                                                 float* __restrict__ dnb,
                                                 int*   __restrict__ eidx,
                                                 float* __restrict__ eidx_f)
{
    __shared__ float4 ca[NL];
    int t = threadIdx.x;
    int base = blockIdx.x << 2;          // 4 rows per block (one per wave)
    int b = base >> 11;
    const float4* src = caw4 + (size_t)b * NL;
#pragma unroll
    for (int r = 0; r < NL/256; r++) ca[t + r*256] = src[t + r*256];
    __syncthreads();

    int w = t >> 6, lane = t & 63;
    int row = base + w;
    int i = row & (NL - 1);
    float4 ci = ca[i];
    float mi = ci.w;

    float df[32];
    unsigned mflags = 0;
    float lmax = 0.0f;
#pragma unroll
    for (int r = 0; r < 32; r++) {
        float4 cj = ca[r*64 + lane];
        float dx = __fsub_rn(ci.x, cj.x);
        float dy = __fsub_rn(ci.y, cj.y);
        float dz = __fsub_rn(ci.z, cj.z);
        float s  = __fadd_rn(__fadd_rn(__fmul_rn(dx,dx), __fmul_rn(dy,dy)), __fmul_rn(dz,dz));
        s = __fadd_rn(s, 1e-6f);
        float m2 = __fmul_rn(mi, cj.w);   // binary mask: 0 or 1
        float d  = __fmul_rn(m2, __fsqrt_rn(s));
        df[r] = d;
        lmax = fmaxf(lmax, d);
        mflags |= (m2 != 0.0f) ? (1u << r) : 0u;
    }
#pragma unroll
    for (int off = 32; off; off >>= 1) lmax = fmaxf(lmax, __shfl_xor(lmax, off));
    unsigned rmb = __float_as_uint(lmax);

    const ull INF = ~0ULL;
    ull m0 = INF, m1 = INF, m2k = INF, m3 = INF;
#pragma unroll
    for (int r = 0; r < 32; r++) {
        unsigned hi = ((mflags >> r) & 1u) ? __float_as_uint(df[r]) : rmb;
        ull key = ((ull)hi << 32) | (unsigned)(r*64 + lane);
        ull a0 = umin64(key, m0); ull k1 = umax64(key, m0); m0 = a0;
        ull a1 = umin64(k1, m1);  ull k2 = umax64(k1, m1);  m1 = a1;
        ull a2 = umin64(k2, m2k); ull k3 = umax64(k2, m2k); m2k = a2;
        m3 = umin64(k3, m3);
    }

    int c = 0;
    ull mykey = 0;
    for (int sel = 0; sel < NK; sel++) {
        ull g = m0;
#pragma unroll
        for (int off = 32; off; off >>= 1) {
            ull o = __shfl_xor(g, off);
            g = o < g ? o : g;
        }
        if (m0 == g) {
            m0 = m1; m1 = m2k; m2k = m3; m3 = INF;
            c++;
            if (m0 == INF && c < 32) {
#pragma unroll
                for (int r = 0; r < 32; r++) {
                    unsigned hi = ((mflags >> r) & 1u) ? __float_as_uint(df[r]) : rmb;
                    ull key = ((ull)hi << 32) | (unsigned)(r*64 + lane);
                    if (key > g) {
                        ull a0 = umin64(key, m0); ull k1 = umax64(key, m0); m0 = a0;
                        ull a1 = umin64(k1, m1);  ull k2 = umax64(k1, m1);  m1 = a1;
                        ull a2 = umin64(k2, m2k); ull k3 = umax64(k2, m2k); m2k = a2;
                        m3 = umin64(k3, m3);
                    }
                }
            }
        }
        mykey = (lane == sel) ? g : mykey;
    }
    if (lane < NK) {
        int g = row * NK + lane;
        int j = (int)(mykey & 0xffffffffULL);
        dnb[g]    = __uint_as_float((unsigned)(mykey >> 32));
        eidx[g]   = j;
        eidx_f[g] = (float)j;
    }
}

// ------- kernel 2: features(fp8) + fp8 MFMA GEMM + LayerNorm, 512 thr / 8 waves -------
// Best-known r12 structure; LN reduce now DPP (VALU) instead of 128 ds_bpermute.
__global__ __launch_bounds__(512, 4) void k_edge(const float4* __restrict__ atoms5,
                                              const int*   __restrict__ eidx,
                                              const float* __restrict__ dnb,
                                              const int*   __restrict__ ridx,
                                              const int*   __restrict__ chl,
                                              const float* __restrict__ posW,
                                              const float* __restrict__ posb,
                                              const unsigned char* __restrict__ Wt,
                                              const float* __restrict__ lns,
                                              const float* __restrict__ lno,
                                              float* __restrict__ Eout)
{
    __shared__ __align__(16) unsigned char fA[BM][FROW];   // 27136 B
    int t = threadIdx.x;
    int base = blockIdx.x * BM;

    int w    = t >> 6;
    int lane = t & 63;
    int l16  = lane & 15;
    int lg   = lane >> 4;
    int g8   = lg * 8;
    int ncol = w * 16;

    // ---- B preload FIRST: 13 x 8B independent loads; latency hides under phase 1.
    const unsigned char* wtb = Wt + (size_t)(ncol + l16) * NEIN + g8;
    long bfr[13];
#pragma unroll
    for (int kt = 0; kt < 13; kt++)
        bfr[kt] = *(const long*)(wtb + kt * 32);

    // ---- phase 1: features, p-split, fp8-packed, b64-pair LDS writes.
    {
        int e = t >> 3;
        int q = t & 7;
        int g = base + e;
        int b = g / (NL * NK);
        int rem = g - b * (NL * NK);
        int i = rem / NK;
        int gi = b * NL + i;
        int j = eidx[g];
        int gj = b * NL + j;

        int off = ridx[gi] - ridx[gj];
        int ec  = (chl[gi] == chl[gj]) ? 1 : 0;
        int dp  = min(max(off + 32, 0), 64);
        dp = ec ? dp : 65;
        {
            float p0 = posW[dp * 16 + 2*q]     + posb[2*q];
            float p1 = posW[dp * 16 + 2*q + 1] + posb[2*q + 1];
            int r = __builtin_amdgcn_cvt_pk_fp8_f32(p0, p1, 0, false);
            *(unsigned short*)&fA[e][q * 2] = (unsigned short)(r & 0xffff);
        }

        const float4* A4 = atoms5 + (size_t)gi * 5;
        const float4* B4 = atoms5 + (size_t)gj * 5;

        auto body = [&](int p) {
            float D;
            if (p == 0) {
                D = dnb[g];
            } else {
                float4 a  = A4[c_PA[p - 1]];
                float4 bb = B4[c_PB[p - 1]];
                float dx = a.x - bb.x, dy = a.y - bb.y, dz = a.z - bb.z;
                D = sqrtf(dx*dx + dy*dy + dz*dz + 1e-6f);
            }
            float tD = D * 0.8f;                  // prescale: z = tD - mu*0.8
            int wds[4];
#pragma unroll
            for (int gq = 0; gq < 4; gq++) {
                float v[4];
#pragma unroll
                for (int u = 0; u < 4; u++) {
                    int s = gq * 4 + u;
                    float z = tD - (1.6f + (float)s * 1.06666667f);
                    v[u] = __expf(-(z * z));
                }
                int r = __builtin_amdgcn_cvt_pk_fp8_f32(v[0], v[1], 0, false);
                r = __builtin_amdgcn_cvt_pk_fp8_f32(v[2], v[3], r, true);
                wds[gq] = r;
            }
            long lo = ((long)(unsigned)wds[1] << 32) | (unsigned)wds[0];
            long hi = ((long)(unsigned)wds[3] << 32) | (unsigned)wds[2];
            *(long*)&fA[e][16 + p * 16]     = lo;
            *(long*)&fA[e][16 + p * 16 + 8] = hi;
        };

#pragma unroll
        for (int pp = 0; pp < 3; pp++) body(q + pp * 8);
        if (q == 0) body(24);
    }

    __syncthreads();

    // ---- phase 2: GEMM. 52 MFMA + 52 conflict-free ds_read_b64 per wave.
    f32x4 acc[4];
#pragma unroll
    for (int mt = 0; mt < 4; mt++) acc[mt] = (f32x4){0.f, 0.f, 0.f, 0.f};

#pragma unroll
    for (int kt = 0; kt < 13; kt++) {
#pragma unroll
        for (int mt = 0; mt < 4; mt++) {
            long a = *(const long*)(&fA[mt * 16 + l16][kt * 32 + g8]);
            acc[mt] = __builtin_amdgcn_mfma_f32_16x16x32_fp8_fp8(a, bfr[kt], acc[mt], 0, 0, 0);
        }
    }

    // ---- phase 3: LayerNorm stats. 16-lane DPP reduce (VALU), combine via LDS.
    float sum[4][4], ssq[4][4];
#pragma unroll
    for (int mt = 0; mt < 4; mt++)
#pragma unroll
        for (int r = 0; r < 4; r++) {
            float v = acc[mt][r];
            sum[mt][r] = row16_sum(v);
            ssq[mt][r] = row16_sum(v * v);
        }

    __syncthreads();                        // all fA reads done -> reuse as scratch
    float* red     = (float*)&fA[0][0];     // [64 rows][8 waves][2] = 4 KB
    float* red2    = red + 1024;            // [64 rows][2] = 512 B
    float* staging = (float*)((char*)&fA[0][0] + 8192);  // 32 rows x SROW f32
    if (l16 == 0) {
#pragma unroll
        for (int mt = 0; mt < 4; mt++)
#pragma unroll
            for (int r = 0; r < 4; r++) {
                int row = mt * 16 + lg * 4 + r;
                red[(row * 8 + w) * 2 + 0] = sum[mt][r];
                red[(row * 8 + w) * 2 + 1] = ssq[mt][r];
            }
    }
    __syncthreads();
    if (t < 64) {
        float ts = 0.f, tq = 0.f;
#pragma unroll
        for (int u = 0; u < 8; u++) {
            ts += red[(t * 8 + u) * 2 + 0];
            tq += red[(t * 8 + u) * 2 + 1];
        }
        float mu  = ts * (1.0f / 128.0f);
        float var = tq * (1.0f / 128.0f) - mu * mu;
        red2[t * 2 + 0] = mu;
        red2[t * 2 + 1] = 1.0f / sqrtf(var + 1e-5f);
    }
    __syncthreads();

    // ---- phase 4: normalized epilogue via LDS staging, non-temporal full-line stores.
    float sc = lns[ncol + l16];
    float of = lno[ncol + l16];
    f32x4* Eout4 = (f32x4*)Eout;
#pragma unroll
    for (int h = 0; h < 2; h++) {
#pragma unroll
        for (int m2 = 0; m2 < 2; m2++) {
            int mt = 2 * h + m2;
#pragma unroll
            for (int r = 0; r < 4; r++) {
                int row  = mt * 16 + lg * 4 + r;      // global row in tile
                int lrow = row - 32 * h;              // 0..31
                float mu = red2[row * 2 + 0];
                float rs = red2[row * 2 + 1];
                staging[lrow * SROW + ncol + l16] =
                    sc * ((acc[mt][r] - mu) * rs) + of;
            }
        }
        __syncthreads();
        // stream out: 1024 f32x4 = 32 rows x 512B, consecutive threads -> consecutive 16B
#pragma unroll
        for (int u = 0; u < 2; u++) {
            int idx  = u * 512 + t;                   // 0..1023
            int lrow = idx >> 5;
            int c4   = idx & 31;
            f32x4 v = *(f32x4*)&staging[lrow * SROW + c4 * 4];
            __builtin_nontemporal_store(v, &Eout4[(size_t)(base + 32 * h + lrow) * 32 + c4]);
        }
        __syncthreads();
    }
}

extern "C" void kernel_launch(void* const* d_in, const int* in_sizes, int n_in,
                              void* d_out, int out_size, void* d_ws, size_t ws_size,
                              hipStream_t stream)
{
    const float* X    = (const float*)d_in[0];
    const float* mask = (const float*)d_in[1];
    const int*   ridx = (const int*)d_in[2];
    const int*   chl  = (const int*)d_in[3];
    const float* posW = (const float*)d_in[4];
    const float* posb = (const float*)d_in[5];
    const float* eW   = (const float*)d_in[6];
    const float* lns  = (const float*)d_in[7];
    const float* lno  = (const float*)d_in[8];

    float* Eout   = (float*)d_out;                                  // B*L*K*128
    float* eidx_f = Eout + (size_t)NB * NL * NK * NEF;              // B*L*K (as float)

    char* ws = (char*)d_ws;
    float4*        atoms5 = (float4*)ws;                            // 327680 B
    float*         dnb    = (float*)(ws + 327680);                  // 491520 B
    int*           eidx   = (int*)(ws + 819200);                    // 491520 B
    unsigned char* Wt     = (unsigned char*)(ws + 1310720);         // 53248 B
    float4*        caw4   = (float4*)(ws + 1363968);                // 65536 B

    k_prep<<<16 + (NEF * (NEIN/2) + 255) / 256, 256, 0, stream>>>(X, mask, eW, atoms5, caw4, Wt);
    k_topk<<<(NB * NL) / 4, 256, 0, stream>>>(caw4, dnb, eidx, eidx_f);
    k_edge<<<(NB * NL * NK) / BM, 512, 0, stream>>>(atoms5, eidx, dnb, ridx, chl,
                                                    posW, posb, Wt, lns, lno, Eout);
}

// Round 16
// 79.577 us; speedup vs baseline: 1.6200x; 1.0522x over previous
//
#include <hip/hip_runtime.h>
#include <math.h>

#define NB 2
#define NL 2048
#define NK 30
#define NEF 128
#define NEIN 416
#define BM 64            // edges per block in k_edge
#define FROW 424         // fA row stride (bytes): conflict-free quarter-wave b64 reads
#define SROW 132         // staging row stride (floats)

typedef float f32x4 __attribute__((ext_vector_type(4)));
typedef unsigned long long ull;

__constant__ int c_PA[24] = {0,2,3,4,1,1,1,1,0,0,0,4,4,3,0,2,3,4,2,3,4,2,3,2};
__constant__ int c_PB[24] = {0,2,3,4,0,2,3,4,2,3,4,2,3,2,1,1,1,1,0,0,0,4,4,3};

__device__ inline ull umin64(ull a, ull b) { return a < b ? a : b; }
__device__ inline ull umax64(ull a, ull b) { return a > b ? a : b; }

// ---- 16-lane f32 sum via DPP (VALU only). Bit-identical to shfl_xor 1,2,4,8.
template<int CTRL>
__device__ inline float dpp_add(float v) {
    int x = __builtin_amdgcn_update_dpp(0, __float_as_int(v), CTRL, 0xF, 0xF, true);
    return v + __int_as_float(x);
}
__device__ inline float row16_sum(float v) {
    v = dpp_add<0xB1>(v);    // quad_perm xor1
    v = dpp_add<0x4E>(v);    // quad_perm xor2
    v = dpp_add<0x141>(v);   // row_half_mirror == xor4
    v = dpp_add<0x140>(v);   // row_mirror      == xor8
    return v;
}

// ---- 64-lane u64 min: DPP for xor1..8, ds_swizzle for xor16, shfl for xor32.
template<int CTRL>
__device__ inline ull dpp_min64(ull v) {
    int lo = __builtin_amdgcn_update_dpp(0, (int)(unsigned)(v & 0xffffffffULL), CTRL, 0xF, 0xF, true);
    int hi = __builtin_amdgcn_update_dpp(0, (int)(unsigned)(v >> 32), CTRL, 0xF, 0xF, true);
    ull o = ((ull)(unsigned)hi << 32) | (unsigned)lo;
    return o < v ? o : v;
}
__device__ inline ull wave_min64(ull v) {
    v = dpp_min64<0xB1>(v);
    v = dpp_min64<0x4E>(v);
    v = dpp_min64<0x141>(v);
    v = dpp_min64<0x140>(v);
    {   // xor16 within each 32-lane half (BitMode: xor=16, and=0x1F)
        int lo = __builtin_amdgcn_ds_swizzle((int)(unsigned)(v & 0xffffffffULL), 0x401F);
        int hi = __builtin_amdgcn_ds_swizzle((int)(unsigned)(v >> 32), 0x401F);
        ull o = ((ull)(unsigned)hi << 32) | (unsigned)lo;
        v = o < v ? o : v;
    }
    {   // xor32
        int lo = __shfl_xor((int)(unsigned)(v & 0xffffffffULL), 32);
        int hi = __shfl_xor((int)(unsigned)(v >> 32), 32);
        ull o = ((ull)(unsigned)hi << 32) | (unsigned)lo;
        v = o < v ? o : v;
    }
    return v;
}

// ---- kernel 0 (merged): blocks 0..15 -> atoms5 + caw4 ; blocks 16.. -> Wt fp8 ----
__global__ void k_prep(const float* __restrict__ X, const float* __restrict__ mask,
                       const float* __restrict__ eW,
                       float4* __restrict__ atoms5, float4* __restrict__ caw4,
                       unsigned char* __restrict__ Wt)
{
    int t = threadIdx.x;
    if (blockIdx.x < 16) {
        int idx = blockIdx.x * 256 + t;           // 16*256 = 4096 = NB*NL exactly
        const float* x = X + (size_t)idx * 12;
        float N[3], Ca[3], C[3], O[3], bv[3], cv[3], av[3];
#pragma unroll
        for (int d = 0; d < 3; d++) { N[d] = x[d]; Ca[d] = x[3+d]; C[d] = x[6+d]; O[d] = x[9+d]; }
#pragma unroll
        for (int d = 0; d < 3; d++) { bv[d] = Ca[d] - N[d]; cv[d] = C[d] - Ca[d]; }
        av[0] = bv[1]*cv[2] - bv[2]*cv[1];
        av[1] = bv[2]*cv[0] - bv[0]*cv[2];
        av[2] = bv[0]*cv[1] - bv[1]*cv[0];
        float4* o = atoms5 + (size_t)idx * 5;
        o[0] = make_float4(N[0], N[1], N[2], 0.f);
        o[1] = make_float4(Ca[0], Ca[1], Ca[2], 0.f);
        o[2] = make_float4(C[0], C[1], C[2], 0.f);
        o[3] = make_float4(O[0], O[1], O[2], 0.f);
        float cb0 = -0.58273431f*av[0] + 0.56802827f*bv[0] - 0.54067466f*cv[0] + Ca[0];
        float cb1 = -0.58273431f*av[1] + 0.56802827f*bv[1] - 0.54067466f*cv[1] + Ca[1];
        float cb2 = -0.58273431f*av[2] + 0.56802827f*bv[2] - 0.54067466f*cv[2] + Ca[2];
        o[4] = make_float4(cb0, cb1, cb2, 0.f);
        caw4[idx] = make_float4(Ca[0], Ca[1], Ca[2], mask[idx]);
    } else {
        int idx = (blockIdx.x - 16) * 256 + t;    // 104*256 = 26624 = NEF*NEIN/2
        if (idx >= NEF * (NEIN / 2)) return;
        int c  = idx / (NEIN / 2);
        int k2 = idx - c * (NEIN / 2);
        float a = eW[(size_t)(2 * k2) * NEF + c];
        float b = eW[(size_t)(2 * k2 + 1) * NEF + c];
        int r = __builtin_amdgcn_cvt_pk_fp8_f32(a, b, 0, false);
        *(unsigned short*)&Wt[(size_t)c * NEIN + 2 * k2] = (unsigned short)(r & 0xffff);
    }
}

// ---- kernel 1: exact top-30, one WAVE per row, 8 rows/block (512 thr) ----
// Selection wave-min now DPP/swizzle (dep chain ~110cy vs ~360cy of ds_bpermute).
// Distance arithmetic: byte-identical __f*_rn chain (selection bit-exact).
__global__ __launch_bounds__(512, 4) void k_topk(const float4* __restrict__ caw4,
                                                 float* __restrict__ dnb,
                                                 int*   __restrict__ eidx,
                                                 float* __restrict__ eidx_f)
{
    __shared__ float4 ca[NL];
    int t = threadIdx.x;
    int base = blockIdx.x << 3;          // 8 rows per block (one per wave)
    int b = base >> 11;
    const float4* src = caw4 + (size_t)b * NL;
#pragma unroll
    for (int r = 0; r < NL/512; r++) ca[t + r*512] = src[t + r*512];
    __syncthreads();

    int w = t >> 6, lane = t & 63;
    int row = base + w;
    int i = row & (NL - 1);
    float4 ci = ca[i];
    float mi = ci.w;

    float df[32];
    unsigned mflags = 0;
    float lmax = 0.0f;
#pragma unroll
    for (int r = 0; r < 32; r++) {
        float4 cj = ca[r*64 + lane];
        float dx = __fsub_rn(ci.x, cj.x);
        float dy = __fsub_rn(ci.y, cj.y);
        float dz = __fsub_rn(ci.z, cj.z);
        float s  = __fadd_rn(__fadd_rn(__fmul_rn(dx,dx), __fmul_rn(dy,dy)), __fmul_rn(dz,dz));
        s = __fadd_rn(s, 1e-6f);
        float m2 = __fmul_rn(mi, cj.w);   // binary mask: 0 or 1
        float d  = __fmul_rn(m2, __fsqrt_rn(s));
        df[r] = d;
        lmax = fmaxf(lmax, d);
        mflags |= (m2 != 0.0f) ? (1u << r) : 0u;
    }
#pragma unroll
    for (int off = 32; off; off >>= 1) lmax = fmaxf(lmax, __shfl_xor(lmax, off));
    unsigned rmb = __float_as_uint(lmax);

    const ull INF = ~0ULL;
    ull m0 = INF, m1 = INF, m2k = INF, m3 = INF;
#pragma unroll
    for (int r = 0; r < 32; r++) {
        unsigned hi = ((mflags >> r) & 1u) ? __float_as_uint(df[r]) : rmb;
        ull key = ((ull)hi << 32) | (unsigned)(r*64 + lane);
        ull a0 = umin64(key, m0); ull k1 = umax64(key, m0); m0 = a0;
        ull a1 = umin64(k1, m1);  ull k2 = umax64(k1, m1);  m1 = a1;
        ull a2 = umin64(k2, m2k); ull k3 = umax64(k2, m2k); m2k = a2;
        m3 = umin64(k3, m3);
    }

    int c = 0;
    ull mykey = 0;
    for (int sel = 0; sel < NK; sel++) {
        ull g = wave_min64(m0);
        if (m0 == g) {
            m0 = m1; m1 = m2k; m2k = m3; m3 = INF;
            c++;
            if (m0 == INF && c < 32) {
#pragma unroll
                for (int r = 0; r < 32; r++) {
                    unsigned hi = ((mflags >> r) & 1u) ? __float_as_uint(df[r]) : rmb;
                    ull key = ((ull)hi << 32) | (unsigned)(r*64 + lane);
                    if (key > g) {
                        ull a0 = umin64(key, m0); ull k1 = umax64(key, m0); m0 = a0;
                        ull a1 = umin64(k1, m1);  ull k2 = umax64(k1, m1);  m1 = a1;
                        ull a2 = umin64(k2, m2k); ull k3 = umax64(k2, m2k); m2k = a2;
                        m3 = umin64(k3, m3);
                    }
                }
            }
        }
        mykey = (lane == sel) ? g : mykey;
    }
    if (lane < NK) {
        int g = row * NK + lane;
        int j = (int)(mykey & 0xffffffffULL);
        dnb[g]    = __uint_as_float((unsigned)(mykey >> 32));
        eidx[g]   = j;
        eidx_f[g] = (float)j;
    }
}

// ------- kernel 2: features(fp8) + fp8 MFMA GEMM + LayerNorm, 512 thr / 8 waves -------
// r15 structure + VALU diet: exp2-domain RBF (3 ops/bin), raw v_sqrt, single int div.
__global__ __launch_bounds__(512, 4) void k_edge(const float4* __restrict__ atoms5,
                                              const int*   __restrict__ eidx,
                                              const float* __restrict__ dnb,
                                              const int*   __restrict__ ridx,
                                              const int*   __restrict__ chl,
                                              const float* __restrict__ posW,
                                              const float* __restrict__ posb,
                                              const unsigned char* __restrict__ Wt,
                                              const float* __restrict__ lns,
                                              const float* __restrict__ lno,
                                              float* __restrict__ Eout)
{
    __shared__ __align__(16) unsigned char fA[BM][FROW];   // 27136 B
    int t = threadIdx.x;
    int base = blockIdx.x * BM;

    int w    = t >> 6;
    int lane = t & 63;
    int l16  = lane & 15;
    int lg   = lane >> 4;
    int g8   = lg * 8;
    int ncol = w * 16;

    // ---- B preload FIRST: 13 x 8B independent loads; latency hides under phase 1.
    const unsigned char* wtb = Wt + (size_t)(ncol + l16) * NEIN + g8;
    long bfr[13];
#pragma unroll
    for (int kt = 0; kt < 13; kt++)
        bfr[kt] = *(const long*)(wtb + kt * 32);

    // ---- phase 1: features, p-split, fp8-packed, exp2-domain RBF.
    {
        int e = t >> 3;
        int q = t & 7;
        int g = base + e;
        int gi = g / 30;                  // exact: g = b*61440 + i*30 + k -> g/30 = b*2048+i
        int b  = gi >> 11;
        int j  = eidx[g];
        int gj = (b << 11) + j;

        int off = ridx[gi] - ridx[gj];
        int ec  = (chl[gi] == chl[gj]) ? 1 : 0;
        int dp  = min(max(off + 32, 0), 64);
        dp = ec ? dp : 65;
        {
            float p0 = posW[dp * 16 + 2*q]     + posb[2*q];
            float p1 = posW[dp * 16 + 2*q + 1] + posb[2*q + 1];
            int r = __builtin_amdgcn_cvt_pk_fp8_f32(p0, p1, 0, false);
            *(unsigned short*)&fA[e][q * 2] = (unsigned short)(r & 0xffff);
        }

        const float4* A4 = atoms5 + (size_t)gi * 5;
        const float4* B4 = atoms5 + (size_t)gj * 5;

        // exp(-(0.8(D-mu_s))^2) = 2^(-(a*D - a*mu_s)^2), a = 0.8*sqrt(log2 e)
        const float A_ = 0.96089792711f;          // 0.8*sqrt(1.44269504089)
        const float C0 = 1.92179585422f;          // A_*2
        const float CS = 1.28119723615f;          // A_*(4/3)
        auto body = [&](int p) {
            float D;
            if (p == 0) {
                D = dnb[g];
            } else {
                float4 a  = A4[c_PA[p - 1]];
                float4 bb = B4[c_PB[p - 1]];
                float dx = a.x - bb.x, dy = a.y - bb.y, dz = a.z - bb.z;
                D = __builtin_amdgcn_sqrtf(dx*dx + dy*dy + dz*dz + 1e-6f);
            }
            float aD = D * A_;
            int wds[4];
#pragma unroll
            for (int gq = 0; gq < 4; gq++) {
                float v[4];
#pragma unroll
                for (int u = 0; u < 4; u++) {
                    int s = gq * 4 + u;
                    float uu = aD - (C0 + (float)s * CS);
                    v[u] = exp2f(-(uu * uu));
                }
                int r = __builtin_amdgcn_cvt_pk_fp8_f32(v[0], v[1], 0, false);
                r = __builtin_amdgcn_cvt_pk_fp8_f32(v[2], v[3], r, true);
                wds[gq] = r;
            }
            long lo = ((long)(unsigned)wds[1] << 32) | (unsigned)wds[0];
            long hi = ((long)(unsigned)wds[3] << 32) | (unsigned)wds[2];
            *(long*)&fA[e][16 + p * 16]     = lo;
            *(long*)&fA[e][16 + p * 16 + 8] = hi;
        };

#pragma unroll
        for (int pp = 0; pp < 3; pp++) body(q + pp * 8);
        if (q == 0) body(24);
    }

    __syncthreads();

    // ---- phase 2: GEMM. 52 MFMA + 52 conflict-free ds_read_b64 per wave.
    f32x4 acc[4];
#pragma unroll
    for (int mt = 0; mt < 4; mt++) acc[mt] = (f32x4){0.f, 0.f, 0.f, 0.f};

#pragma unroll
    for (int kt = 0; kt < 13; kt++) {
#pragma unroll
        for (int mt = 0; mt < 4; mt++) {
            long a = *(const long*)(&fA[mt * 16 + l16][kt * 32 + g8]);
            acc[mt] = __builtin_amdgcn_mfma_f32_16x16x32_fp8_fp8(a, bfr[kt], acc[mt], 0, 0, 0);
        }
    }

    // ---- phase 3: LayerNorm stats. 16-lane DPP reduce (VALU), combine via LDS.
    float sum[4][4], ssq[4][4];
#pragma unroll
    for (int mt = 0; mt < 4; mt++)
#pragma unroll
        for (int r = 0; r < 4; r++) {
            float v = acc[mt][r];
            sum[mt][r] = row16_sum(v);
            ssq[mt][r] = row16_sum(v * v);
        }

    __syncthreads();                        // all fA reads done -> reuse as scratch
    float* red     = (float*)&fA[0][0];     // [64 rows][8 waves][2] = 4 KB
    float* red2    = red + 1024;            // [64 rows][2] = 512 B
    float* staging = (float*)((char*)&fA[0][0] + 8192);  // 32 rows x SROW f32
    if (l16 == 0) {
#pragma unroll
        for (int mt = 0; mt < 4; mt++)
#pragma unroll
            for (int r = 0; r < 4; r++) {
                int row = mt * 16 + lg * 4 + r;
                red[(row * 8 + w) * 2 + 0] = sum[mt][r];
                red[(row * 8 + w) * 2 + 1] = ssq[mt][r];
            }
    }
    __syncthreads();
    if (t < 64) {
        float ts = 0.f, tq = 0.f;
#pragma unroll
        for (int u = 0; u < 8; u++) {
            ts += red[(t * 8 + u) * 2 + 0];
            tq += red[(t * 8 + u) * 2 + 1];
        }
        float mu  = ts * (1.0f / 128.0f);
        float var = tq * (1.0f / 128.0f) - mu * mu;
        red2[t * 2 + 0] = mu;
        red2[t * 2 + 1] = 1.0f / sqrtf(var + 1e-5f);
    }
    __syncthreads();

    // ---- phase 4: normalized epilogue via LDS staging, non-temporal full-line stores.
    float sc = lns[ncol + l16];
    float of = lno[ncol + l16];
    f32x4* Eout4 = (f32x4*)Eout;
#pragma unroll
    for (int h = 0; h < 2; h++) {
#pragma unroll
        for (int m2 = 0; m2 < 2; m2++) {
            int mt = 2 * h + m2;
#pragma unroll
            for (int r = 0; r < 4; r++) {
                int row  = mt * 16 + lg * 4 + r;      // global row in tile
                int lrow = row - 32 * h;              // 0..31
                float mu = red2[row * 2 + 0];
                float rs = red2[row * 2 + 1];
                staging[lrow * SROW + ncol + l16] =
                    sc * ((acc[mt][r] - mu) * rs) + of;
            }
        }
        __syncthreads();
#pragma unroll
        for (int u = 0; u < 2; u++) {
            int idx  = u * 512 + t;                   // 0..1023
            int lrow = idx >> 5;
            int c4   = idx & 31;
            f32x4 v = *(f32x4*)&staging[lrow * SROW + c4 * 4];
            __builtin_nontemporal_store(v, &Eout4[(size_t)(base + 32 * h + lrow) * 32 + c4]);
        }
        __syncthreads();
    }
}

extern "C" void kernel_launch(void* const* d_in, const int* in_sizes, int n_in,
                              void* d_out, int out_size, void* d_ws, size_t ws_size,
                              hipStream_t stream)
{
    const float* X    = (const float*)d_in[0];
    const float* mask = (const float*)d_in[1];
    const int*   ridx = (const int*)d_in[2];
    const int*   chl  = (const int*)d_in[3];
    const float* posW = (const float*)d_in[4];
    const float* posb = (const float*)d_in[5];
    const float* eW   = (const float*)d_in[6];
    const float* lns  = (const float*)d_in[7];
    const float* lno  = (const float*)d_in[8];

    float* Eout   = (float*)d_out;                                  // B*L*K*128
    float* eidx_f = Eout + (size_t)NB * NL * NK * NEF;              // B*L*K (as float)

    char* ws = (char*)d_ws;
    float4*        atoms5 = (float4*)ws;                            // 327680 B
    float*         dnb    = (float*)(ws + 327680);                  // 491520 B
    int*           eidx   = (int*)(ws + 819200);                    // 491520 B
    unsigned char* Wt     = (unsigned char*)(ws + 1310720);         // 53248 B
    float4*        caw4   = (float4*)(ws + 1363968);                // 65536 B

    k_prep<<<16 + (NEF * (NEIN/2) + 255) / 256, 256, 0, stream>>>(X, mask, eW, atoms5, caw4, Wt);
    k_topk<<<(NB * NL) / 8, 512, 0, stream>>>(caw4, dnb, eidx, eidx_f);
    k_edge<<<(NB * NL * NK) / BM, 512, 0, stream>>>(atoms5, eidx, dnb, ridx, chl,
                                                    posW, posb, Wt, lns, lno, Eout);
}

// Round 17
// 76.758 us; speedup vs baseline: 1.6795x; 1.0367x over previous
//
#include <hip/hip_runtime.h>
#include <math.h>

#define NB 2
#define NL 2048
#define NK 30
#define NEF 128
#define NEIN 416
#define BM 64            // edges per block in k_edge
#define FROW 424         // fA row stride (bytes): conflict-free quarter-wave b64 reads
#define SROW 132         // staging row stride (floats)

typedef float f32x4 __attribute__((ext_vector_type(4)));
typedef unsigned long long ull;

__constant__ int c_PA[24] = {0,2,3,4,1,1,1,1,0,0,0,4,4,3,0,2,3,4,2,3,4,2,3,2};
__constant__ int c_PB[24] = {0,2,3,4,0,2,3,4,2,3,4,2,3,2,1,1,1,1,0,0,0,4,4,3};

__device__ inline ull umin64(ull a, ull b) { return a < b ? a : b; }
__device__ inline ull umax64(ull a, ull b) { return a > b ? a : b; }

// ---- 16-lane f32 sum via DPP (VALU only). Bit-identical to shfl_xor 1,2,4,8.
template<int CTRL>
__device__ inline float dpp_add(float v) {
    int x = __builtin_amdgcn_update_dpp(0, __float_as_int(v), CTRL, 0xF, 0xF, true);
    return v + __int_as_float(x);
}
__device__ inline float row16_sum(float v) {
    v = dpp_add<0xB1>(v);    // quad_perm xor1
    v = dpp_add<0x4E>(v);    // quad_perm xor2
    v = dpp_add<0x141>(v);   // row_half_mirror == xor4
    v = dpp_add<0x140>(v);   // row_mirror      == xor8
    return v;
}

// ---- 64-lane u64 min: DPP for xor1..8, ds_swizzle for xor16, shfl for xor32.
template<int CTRL>
__device__ inline ull dpp_min64(ull v) {
    int lo = __builtin_amdgcn_update_dpp(0, (int)(unsigned)(v & 0xffffffffULL), CTRL, 0xF, 0xF, true);
    int hi = __builtin_amdgcn_update_dpp(0, (int)(unsigned)(v >> 32), CTRL, 0xF, 0xF, true);
    ull o = ((ull)(unsigned)hi << 32) | (unsigned)lo;
    return o < v ? o : v;
}
__device__ inline ull wave_min64(ull v) {
    v = dpp_min64<0xB1>(v);
    v = dpp_min64<0x4E>(v);
    v = dpp_min64<0x141>(v);
    v = dpp_min64<0x140>(v);
    {   // xor16 within each 32-lane half (BitMode: xor=16, and=0x1F)
        int lo = __builtin_amdgcn_ds_swizzle((int)(unsigned)(v & 0xffffffffULL), 0x401F);
        int hi = __builtin_amdgcn_ds_swizzle((int)(unsigned)(v >> 32), 0x401F);
        ull o = ((ull)(unsigned)hi << 32) | (unsigned)lo;
        v = o < v ? o : v;
    }
    {   // xor32
        int lo = __shfl_xor((int)(unsigned)(v & 0xffffffffULL), 32);
        int hi = __shfl_xor((int)(unsigned)(v >> 32), 32);
        ull o = ((ull)(unsigned)hi << 32) | (unsigned)lo;
        v = o < v ? o : v;
    }
    return v;
}

// ---- kernel 0 (merged): blocks 0..15 -> atoms5 + caw4 ; blocks 16.. -> Wt fp8 ----
__global__ void k_prep(const float* __restrict__ X, const float* __restrict__ mask,
                       const float* __restrict__ eW,
                       float4* __restrict__ atoms5, float4* __restrict__ caw4,
                       unsigned char* __restrict__ Wt)
{
    int t = threadIdx.x;
    if (blockIdx.x < 16) {
        int idx = blockIdx.x * 256 + t;           // 16*256 = 4096 = NB*NL exactly
        const float* x = X + (size_t)idx * 12;
        float N[3], Ca[3], C[3], O[3], bv[3], cv[3], av[3];
#pragma unroll
        for (int d = 0; d < 3; d++) { N[d] = x[d]; Ca[d] = x[3+d]; C[d] = x[6+d]; O[d] = x[9+d]; }
#pragma unroll
        for (int d = 0; d < 3; d++) { bv[d] = Ca[d] - N[d]; cv[d] = C[d] - Ca[d]; }
        av[0] = bv[1]*cv[2] - bv[2]*cv[1];
        av[1] = bv[2]*cv[0] - bv[0]*cv[2];
        av[2] = bv[0]*cv[1] - bv[1]*cv[0];
        float4* o = atoms5 + (size_t)idx * 5;
        o[0] = make_float4(N[0], N[1], N[2], 0.f);
        o[1] = make_float4(Ca[0], Ca[1], Ca[2], 0.f);
        o[2] = make_float4(C[0], C[1], C[2], 0.f);
        o[3] = make_float4(O[0], O[1], O[2], 0.f);
        float cb0 = -0.58273431f*av[0] + 0.56802827f*bv[0] - 0.54067466f*cv[0] + Ca[0];
        float cb1 = -0.58273431f*av[1] + 0.56802827f*bv[1] - 0.54067466f*cv[1] + Ca[1];
        float cb2 = -0.58273431f*av[2] + 0.56802827f*bv[2] - 0.54067466f*cv[2] + Ca[2];
        o[4] = make_float4(cb0, cb1, cb2, 0.f);
        caw4[idx] = make_float4(Ca[0], Ca[1], Ca[2], mask[idx]);
    } else {
        int idx = (blockIdx.x - 16) * 256 + t;    // 104*256 = 26624 = NEF*NEIN/2
        if (idx >= NEF * (NEIN / 2)) return;
        int c  = idx / (NEIN / 2);
        int k2 = idx - c * (NEIN / 2);
        float a = eW[(size_t)(2 * k2) * NEF + c];
        float b = eW[(size_t)(2 * k2 + 1) * NEF + c];
        int r = __builtin_amdgcn_cvt_pk_fp8_f32(a, b, 0, false);
        *(unsigned short*)&Wt[(size_t)c * NEIN + 2 * k2] = (unsigned short)(r & 0xffff);
    }
}

// ---- kernel 1: exact top-30, one WAVE per row, 8 rows/block (512 thr) ----
__global__ __launch_bounds__(512, 4) void k_topk(const float4* __restrict__ caw4,
                                                 float* __restrict__ dnb,
                                                 int*   __restrict__ eidx,
                                                 float* __restrict__ eidx_f)
{
    __shared__ float4 ca[NL];
    int t = threadIdx.x;
    int base = blockIdx.x << 3;          // 8 rows per block (one per wave)
    int b = base >> 11;
    const float4* src = caw4 + (size_t)b * NL;
#pragma unroll
    for (int r = 0; r < NL/512; r++) ca[t + r*512] = src[t + r*512];
    __syncthreads();

    int w = t >> 6, lane = t & 63;
    int row = base + w;
    int i = row & (NL - 1);
    float4 ci = ca[i];
    float mi = ci.w;

    float df[32];
    unsigned mflags = 0;
    float lmax = 0.0f;
#pragma unroll
    for (int r = 0; r < 32; r++) {
        float4 cj = ca[r*64 + lane];
        float dx = __fsub_rn(ci.x, cj.x);
        float dy = __fsub_rn(ci.y, cj.y);
        float dz = __fsub_rn(ci.z, cj.z);
        float s  = __fadd_rn(__fadd_rn(__fmul_rn(dx,dx), __fmul_rn(dy,dy)), __fmul_rn(dz,dz));
        s = __fadd_rn(s, 1e-6f);
        float m2 = __fmul_rn(mi, cj.w);   // binary mask: 0 or 1
        float d  = __fmul_rn(m2, __fsqrt_rn(s));
        df[r] = d;
        lmax = fmaxf(lmax, d);
        mflags |= (m2 != 0.0f) ? (1u << r) : 0u;
    }
#pragma unroll
    for (int off = 32; off; off >>= 1) lmax = fmaxf(lmax, __shfl_xor(lmax, off));
    unsigned rmb = __float_as_uint(lmax);

    const ull INF = ~0ULL;
    ull m0 = INF, m1 = INF, m2k = INF, m3 = INF;
#pragma unroll
    for (int r = 0; r < 32; r++) {
        unsigned hi = ((mflags >> r) & 1u) ? __float_as_uint(df[r]) : rmb;
        ull key = ((ull)hi << 32) | (unsigned)(r*64 + lane);
        ull a0 = umin64(key, m0); ull k1 = umax64(key, m0); m0 = a0;
        ull a1 = umin64(k1, m1);  ull k2 = umax64(k1, m1);  m1 = a1;
        ull a2 = umin64(k2, m2k); ull k3 = umax64(k2, m2k); m2k = a2;
        m3 = umin64(k3, m3);
    }

    int c = 0;
    ull mykey = 0;
    for (int sel = 0; sel < NK; sel++) {
        ull g = wave_min64(m0);
        if (m0 == g) {
            m0 = m1; m1 = m2k; m2k = m3; m3 = INF;
            c++;
            if (m0 == INF && c < 32) {
#pragma unroll
                for (int r = 0; r < 32; r++) {
                    unsigned hi = ((mflags >> r) & 1u) ? __float_as_uint(df[r]) : rmb;
                    ull key = ((ull)hi << 32) | (unsigned)(r*64 + lane);
                    if (key > g) {
                        ull a0 = umin64(key, m0); ull k1 = umax64(key, m0); m0 = a0;
                        ull a1 = umin64(k1, m1);  ull k2 = umax64(k1, m1);  m1 = a1;
                        ull a2 = umin64(k2, m2k); ull k3 = umax64(k2, m2k); m2k = a2;
                        m3 = umin64(k3, m3);
                    }
                }
            }
        }
        mykey = (lane == sel) ? g : mykey;
    }
    if (lane < NK) {
        int g = row * NK + lane;
        int j = (int)(mykey & 0xffffffffULL);
        dnb[g]    = __uint_as_float((unsigned)(mykey >> 32));
        eidx[g]   = j;
        eidx_f[g] = (float)j;
    }
}

// ------- kernel 2: features(fp8) + fp8 MFMA GEMM + LayerNorm, 512 thr / 8 waves -------
// Raw v_exp_f32 (exp2-domain); single-pass epilogue: 5 barriers, NT stream LAST,
// no trailing barrier (waves retire while stores drain).
__global__ __launch_bounds__(512, 4) void k_edge(const float4* __restrict__ atoms5,
                                              const int*   __restrict__ eidx,
                                              const float* __restrict__ dnb,
                                              const int*   __restrict__ ridx,
                                              const int*   __restrict__ chl,
                                              const float* __restrict__ posW,
                                              const float* __restrict__ posb,
                                              const unsigned char* __restrict__ Wt,
                                              const float* __restrict__ lns,
                                              const float* __restrict__ lno,
                                              float* __restrict__ Eout)
{
    // LDS union: phase A: fA[64][424] = 27136 B
    //            phase B: red[1024f] + red2[128f] + staging[64*132f] = 38400 B
    __shared__ __align__(16) unsigned char smem[38400];
    unsigned char (*fA)[FROW] = (unsigned char (*)[FROW])smem;
    int t = threadIdx.x;
    int base = blockIdx.x * BM;

    int w    = t >> 6;
    int lane = t & 63;
    int l16  = lane & 15;
    int lg   = lane >> 4;
    int g8   = lg * 8;
    int ncol = w * 16;

    // ---- B preload FIRST: 13 x 8B independent loads; latency hides under phase 1.
    const unsigned char* wtb = Wt + (size_t)(ncol + l16) * NEIN + g8;
    long bfr[13];
#pragma unroll
    for (int kt = 0; kt < 13; kt++)
        bfr[kt] = *(const long*)(wtb + kt * 32);

    // ---- phase 1: features, p-split, fp8-packed, exp2-domain RBF (raw v_exp).
    {
        int e = t >> 3;
        int q = t & 7;
        int g = base + e;
        int gi = g / 30;                  // exact: g = b*61440 + i*30 + k
        int b  = gi >> 11;
        int j  = eidx[g];
        int gj = (b << 11) + j;

        int off = ridx[gi] - ridx[gj];
        int ec  = (chl[gi] == chl[gj]) ? 1 : 0;
        int dp  = min(max(off + 32, 0), 64);
        dp = ec ? dp : 65;
        {
            float p0 = posW[dp * 16 + 2*q]     + posb[2*q];
            float p1 = posW[dp * 16 + 2*q + 1] + posb[2*q + 1];
            int r = __builtin_amdgcn_cvt_pk_fp8_f32(p0, p1, 0, false);
            *(unsigned short*)&fA[e][q * 2] = (unsigned short)(r & 0xffff);
        }

        const float4* A4 = atoms5 + (size_t)gi * 5;
        const float4* B4 = atoms5 + (size_t)gj * 5;

        // exp(-(0.8(D-mu_s))^2) = 2^(-(a*D - a*mu_s)^2), a = 0.8*sqrt(log2 e)
        const float A_ = 0.96089792711f;
        const float C0 = 1.92179585422f;          // A_*2
        const float CS = 1.28119723615f;          // A_*(4/3)
        auto body = [&](int p) {
            float D;
            if (p == 0) {
                D = dnb[g];
            } else {
                float4 a  = A4[c_PA[p - 1]];
                float4 bb = B4[c_PB[p - 1]];
                float dx = a.x - bb.x, dy = a.y - bb.y, dz = a.z - bb.z;
                D = __builtin_amdgcn_sqrtf(dx*dx + dy*dy + dz*dz + 1e-6f);
            }
            float aD = D * A_;
            int wds[4];
#pragma unroll
            for (int gq = 0; gq < 4; gq++) {
                float v[4];
#pragma unroll
                for (int u = 0; u < 4; u++) {
                    int s = gq * 4 + u;
                    float uu = aD - (C0 + (float)s * CS);
                    v[u] = __builtin_amdgcn_exp2f(-(uu * uu));   // raw v_exp_f32
                }
                int r = __builtin_amdgcn_cvt_pk_fp8_f32(v[0], v[1], 0, false);
                r = __builtin_amdgcn_cvt_pk_fp8_f32(v[2], v[3], r, true);
                wds[gq] = r;
            }
            long lo = ((long)(unsigned)wds[1] << 32) | (unsigned)wds[0];
            long hi = ((long)(unsigned)wds[3] << 32) | (unsigned)wds[2];
            *(long*)&fA[e][16 + p * 16]     = lo;
            *(long*)&fA[e][16 + p * 16 + 8] = hi;
        };

#pragma unroll
        for (int pp = 0; pp < 3; pp++) body(q + pp * 8);
        if (q == 0) body(24);
    }

    __syncthreads();                               // B1

    // ---- phase 2: GEMM. 52 MFMA + 52 conflict-free ds_read_b64 per wave.
    f32x4 acc[4];
#pragma unroll
    for (int mt = 0; mt < 4; mt++) acc[mt] = (f32x4){0.f, 0.f, 0.f, 0.f};

#pragma unroll
    for (int kt = 0; kt < 13; kt++) {
#pragma unroll
        for (int mt = 0; mt < 4; mt++) {
            long a = *(const long*)(&fA[mt * 16 + l16][kt * 32 + g8]);
            acc[mt] = __builtin_amdgcn_mfma_f32_16x16x32_fp8_fp8(a, bfr[kt], acc[mt], 0, 0, 0);
        }
    }

    // ---- phase 3: LayerNorm stats. 16-lane DPP reduce (VALU), combine via LDS.
    float sum[4][4], ssq[4][4];
#pragma unroll
    for (int mt = 0; mt < 4; mt++)
#pragma unroll
        for (int r = 0; r < 4; r++) {
            float v = acc[mt][r];
            sum[mt][r] = row16_sum(v);
            ssq[mt][r] = row16_sum(v * v);
        }

    __syncthreads();                               // B2: all fA reads done, reuse LDS
    float* red     = (float*)smem;                 // [64 rows][8 waves][2] = 4 KB
    float* red2    = red + 1024;                   // [64 rows][2] = 512 B
    float* staging = red2 + 128;                   // [64 rows][SROW] = 33792 B
    if (l16 == 0) {
#pragma unroll
        for (int mt = 0; mt < 4; mt++)
#pragma unroll
            for (int r = 0; r < 4; r++) {
                int row = mt * 16 + lg * 4 + r;
                red[(row * 8 + w) * 2 + 0] = sum[mt][r];
                red[(row * 8 + w) * 2 + 1] = ssq[mt][r];
            }
    }
    __syncthreads();                               // B3
    if (t < 64) {
        float ts = 0.f, tq = 0.f;
#pragma unroll
        for (int u = 0; u < 8; u++) {
            ts += red[(t * 8 + u) * 2 + 0];
            tq += red[(t * 8 + u) * 2 + 1];
        }
        float mu  = ts * (1.0f / 128.0f);
        float var = tq * (1.0f / 128.0f) - mu * mu;
        red2[t * 2 + 0] = mu;
        red2[t * 2 + 1] = 1.0f / sqrtf(var + 1e-5f);
    }
    __syncthreads();                               // B4

    // ---- phase 4: single staging pass (all 64 rows), NT stream LAST, no barrier after.
    float sc = lns[ncol + l16];
    float of = lno[ncol + l16];
#pragma unroll
    for (int mt = 0; mt < 4; mt++)
#pragma unroll
        for (int r = 0; r < 4; r++) {
            int row = mt * 16 + lg * 4 + r;
            float mu = red2[row * 2 + 0];
            float rs = red2[row * 2 + 1];
            staging[row * SROW + ncol + l16] =
                sc * ((acc[mt][r] - mu) * rs) + of;
        }
    __syncthreads();                               // B5

    f32x4* Eout4 = (f32x4*)Eout;
#pragma unroll
    for (int u = 0; u < 4; u++) {
        int idx  = u * 512 + t;                    // 0..2047
        int lrow = idx >> 5;
        int c4   = idx & 31;
        f32x4 val = *(f32x4*)&staging[lrow * SROW + c4 * 4];
        __builtin_nontemporal_store(val, &Eout4[(size_t)(base + lrow) * 32 + c4]);
    }
    // no trailing barrier: stores drain as waves retire
}

extern "C" void kernel_launch(void* const* d_in, const int* in_sizes, int n_in,
                              void* d_out, int out_size, void* d_ws, size_t ws_size,
                              hipStream_t stream)
{
    const float* X    = (const float*)d_in[0];
    const float* mask = (const float*)d_in[1];
    const int*   ridx = (const int*)d_in[2];
    const int*   chl  = (const int*)d_in[3];
    const float* posW = (const float*)d_in[4];
    const float* posb = (const float*)d_in[5];
    const float* eW   = (const float*)d_in[6];
    const float* lns  = (const float*)d_in[7];
    const float* lno  = (const float*)d_in[8];

    float* Eout   = (float*)d_out;                                  // B*L*K*128
    float* eidx_f = Eout + (size_t)NB * NL * NK * NEF;              // B*L*K (as float)

    char* ws = (char*)d_ws;
    float4*        atoms5 = (float4*)ws;                            // 327680 B
    float*         dnb    = (float*)(ws + 327680);                  // 491520 B
    int*           eidx   = (int*)(ws + 819200);                    // 491520 B
    unsigned char* Wt     = (unsigned char*)(ws + 1310720);         // 53248 B
    float4*        caw4   = (float4*)(ws + 1363968);                // 65536 B

    k_prep<<<16 + (NEF * (NEIN/2) + 255) / 256, 256, 0, stream>>>(X, mask, eW, atoms5, caw4, Wt);
    k_topk<<<(NB * NL) / 8, 512, 0, stream>>>(caw4, dnb, eidx, eidx_f);
    k_edge<<<(NB * NL * NK) / BM, 512, 0, stream>>>(atoms5, eidx, dnb, ridx, chl,
                                                    posW, posb, Wt, lns, lno, Eout);
}

// Round 18
// 71.657 us; speedup vs baseline: 1.7991x; 1.0712x over previous
//
#include <hip/hip_runtime.h>
#include <math.h>

#define NB 2
#define NL 2048
#define NK 30
#define NEF 128
#define NEIN 416
#define BM 64            // edges per block in k_edge
#define FROW 424         // fA row stride (bytes): conflict-free quarter-wave b64 reads
#define SROW 132         // staging row stride (floats)

typedef float f32x4 __attribute__((ext_vector_type(4)));
typedef unsigned long long ull;

__constant__ int c_PA[24] = {0,2,3,4,1,1,1,1,0,0,0,4,4,3,0,2,3,4,2,3,4,2,3,2};
__constant__ int c_PB[24] = {0,2,3,4,0,2,3,4,2,3,4,2,3,2,1,1,1,1,0,0,0,4,4,3};

__device__ inline ull umin64(ull a, ull b) { return a < b ? a : b; }
__device__ inline ull umax64(ull a, ull b) { return a > b ? a : b; }

// ---- 16-lane f32 sum via DPP (VALU only). Bit-identical to shfl_xor 1,2,4,8.
template<int CTRL>
__device__ inline float dpp_add(float v) {
    int x = __builtin_amdgcn_update_dpp(0, __float_as_int(v), CTRL, 0xF, 0xF, true);
    return v + __int_as_float(x);
}
__device__ inline float row16_sum(float v) {
    v = dpp_add<0xB1>(v);    // quad_perm xor1
    v = dpp_add<0x4E>(v);    // quad_perm xor2
    v = dpp_add<0x141>(v);   // row_half_mirror == xor4
    v = dpp_add<0x140>(v);   // row_mirror      == xor8
    return v;
}

// ---- 64-lane u64 min: DPP for xor1..8, ds_swizzle for xor16, shfl for xor32.
template<int CTRL>
__device__ inline ull dpp_min64(ull v) {
    int lo = __builtin_amdgcn_update_dpp(0, (int)(unsigned)(v & 0xffffffffULL), CTRL, 0xF, 0xF, true);
    int hi = __builtin_amdgcn_update_dpp(0, (int)(unsigned)(v >> 32), CTRL, 0xF, 0xF, true);
    ull o = ((ull)(unsigned)hi << 32) | (unsigned)lo;
    return o < v ? o : v;
}
__device__ inline ull wave_min64(ull v) {
    v = dpp_min64<0xB1>(v);
    v = dpp_min64<0x4E>(v);
    v = dpp_min64<0x141>(v);
    v = dpp_min64<0x140>(v);
    {   // xor16 within each 32-lane half (BitMode: xor=16, and=0x1F)
        int lo = __builtin_amdgcn_ds_swizzle((int)(unsigned)(v & 0xffffffffULL), 0x401F);
        int hi = __builtin_amdgcn_ds_swizzle((int)(unsigned)(v >> 32), 0x401F);
        ull o = ((ull)(unsigned)hi << 32) | (unsigned)lo;
        v = o < v ? o : v;
    }
    {   // xor32
        int lo = __shfl_xor((int)(unsigned)(v & 0xffffffffULL), 32);
        int hi = __shfl_xor((int)(unsigned)(v >> 32), 32);
        ull o = ((ull)(unsigned)hi << 32) | (unsigned)lo;
        v = o < v ? o : v;
    }
    return v;
}

// ---- kernel 1 (merged front): blocks 0..511 = topk (self-staged from X);
//      blocks 512..519 = atoms5 prep; blocks 520..571 = Wt fp8 prep.
__global__ __launch_bounds__(512, 4) void k_front(const float* __restrict__ X,
                                                  const float* __restrict__ mask,
                                                  const float* __restrict__ eW,
                                                  float4* __restrict__ atoms5,
                                                  unsigned char* __restrict__ Wt,
                                                  float* __restrict__ dnb,
                                                  int*   __restrict__ eidx,
                                                  float* __restrict__ eidx_f)
{
    __shared__ float4 ca[NL];
    int t = threadIdx.x;

    if (blockIdx.x >= 512) {
        if (blockIdx.x < 520) {
            // atoms5: [N,Ca,C,O,Cb] as 5x float4 per residue
            int idx = (blockIdx.x - 512) * 512 + t;       // 8*512 = 4096
            const float* x = X + (size_t)idx * 12;
            float N[3], Ca[3], C[3], O[3], bv[3], cv[3], av[3];
#pragma unroll
            for (int d = 0; d < 3; d++) { N[d] = x[d]; Ca[d] = x[3+d]; C[d] = x[6+d]; O[d] = x[9+d]; }
#pragma unroll
            for (int d = 0; d < 3; d++) { bv[d] = Ca[d] - N[d]; cv[d] = C[d] - Ca[d]; }
            av[0] = bv[1]*cv[2] - bv[2]*cv[1];
            av[1] = bv[2]*cv[0] - bv[0]*cv[2];
            av[2] = bv[0]*cv[1] - bv[1]*cv[0];
            float4* o = atoms5 + (size_t)idx * 5;
            o[0] = make_float4(N[0], N[1], N[2], 0.f);
            o[1] = make_float4(Ca[0], Ca[1], Ca[2], 0.f);
            o[2] = make_float4(C[0], C[1], C[2], 0.f);
            o[3] = make_float4(O[0], O[1], O[2], 0.f);
            float cb0 = -0.58273431f*av[0] + 0.56802827f*bv[0] - 0.54067466f*cv[0] + Ca[0];
            float cb1 = -0.58273431f*av[1] + 0.56802827f*bv[1] - 0.54067466f*cv[1] + Ca[1];
            float cb2 = -0.58273431f*av[2] + 0.56802827f*bv[2] - 0.54067466f*cv[2] + Ca[2];
            o[4] = make_float4(cb0, cb1, cb2, 0.f);
        } else {
            // Wt: W (416x128 f32) -> (128x416 fp8 e4m3)
            int idx = (blockIdx.x - 520) * 512 + t;       // 52*512 = 26624
            if (idx < NEF * (NEIN / 2)) {
                int c  = idx / (NEIN / 2);
                int k2 = idx - c * (NEIN / 2);
                float a = eW[(size_t)(2 * k2) * NEF + c];
                float b = eW[(size_t)(2 * k2 + 1) * NEF + c];
                int r = __builtin_amdgcn_cvt_pk_fp8_f32(a, b, 0, false);
                *(unsigned short*)&Wt[(size_t)c * NEIN + 2 * k2] = (unsigned short)(r & 0xffff);
            }
        }
        return;
    }

    // ---- topk: 8 rows per block, one wave per row; stage (Ca.xyz, mask) from X.
    int base = blockIdx.x << 3;
    int b = base >> 11;
    const float* Xb = X + (size_t)b * NL * 12;
    const float* mb = mask + (size_t)b * NL;
#pragma unroll
    for (int r = 0; r < NL/512; r++) {
        int j = t + r * 512;
        ca[j] = make_float4(Xb[j*12+3], Xb[j*12+4], Xb[j*12+5], mb[j]);
    }
    __syncthreads();

    int w = t >> 6, lane = t & 63;
    int row = base + w;
    int i = row & (NL - 1);
    float4 ci = ca[i];
    float mi = ci.w;

    float df[32];
    unsigned mflags = 0;
    float lmax = 0.0f;
#pragma unroll
    for (int r = 0; r < 32; r++) {
        float4 cj = ca[r*64 + lane];
        float dx = __fsub_rn(ci.x, cj.x);
        float dy = __fsub_rn(ci.y, cj.y);
        float dz = __fsub_rn(ci.z, cj.z);
        float s  = __fadd_rn(__fadd_rn(__fmul_rn(dx,dx), __fmul_rn(dy,dy)), __fmul_rn(dz,dz));
        s = __fadd_rn(s, 1e-6f);
        float m2 = __fmul_rn(mi, cj.w);   // binary mask: 0 or 1
        float d  = __fmul_rn(m2, __fsqrt_rn(s));
        df[r] = d;
        lmax = fmaxf(lmax, d);
        mflags |= (m2 != 0.0f) ? (1u << r) : 0u;
    }
#pragma unroll
    for (int off = 32; off; off >>= 1) lmax = fmaxf(lmax, __shfl_xor(lmax, off));
    unsigned rmb = __float_as_uint(lmax);

    const ull INF = ~0ULL;
    ull m0 = INF, m1 = INF, m2k = INF, m3 = INF;
#pragma unroll
    for (int r = 0; r < 32; r++) {
        unsigned hi = ((mflags >> r) & 1u) ? __float_as_uint(df[r]) : rmb;
        ull key = ((ull)hi << 32) | (unsigned)(r*64 + lane);
        ull a0 = umin64(key, m0); ull k1 = umax64(key, m0); m0 = a0;
        ull a1 = umin64(k1, m1);  ull k2 = umax64(k1, m1);  m1 = a1;
        ull a2 = umin64(k2, m2k); ull k3 = umax64(k2, m2k); m2k = a2;
        m3 = umin64(k3, m3);
    }

    int c = 0;
    ull mykey = 0;
    for (int sel = 0; sel < NK; sel++) {
        ull g = wave_min64(m0);
        if (m0 == g) {
            m0 = m1; m1 = m2k; m2k = m3; m3 = INF;
            c++;
            if (m0 == INF && c < 32) {
#pragma unroll
                for (int r = 0; r < 32; r++) {
                    unsigned hi = ((mflags >> r) & 1u) ? __float_as_uint(df[r]) : rmb;
                    ull key = ((ull)hi << 32) | (unsigned)(r*64 + lane);
                    if (key > g) {
                        ull a0 = umin64(key, m0); ull k1 = umax64(key, m0); m0 = a0;
                        ull a1 = umin64(k1, m1);  ull k2 = umax64(k1, m1);  m1 = a1;
                        ull a2 = umin64(k2, m2k); ull k3 = umax64(k2, m2k); m2k = a2;
                        m3 = umin64(k3, m3);
                    }
                }
            }
        }
        mykey = (lane == sel) ? g : mykey;
    }
    if (lane < NK) {
        int g = row * NK + lane;
        int j = (int)(mykey & 0xffffffffULL);
        dnb[g]    = __uint_as_float((unsigned)(mykey >> 32));
        eidx[g]   = j;
        eidx_f[g] = (float)j;
    }
}

// ------- kernel 2: features(fp8) + fp8 MFMA GEMM + LayerNorm, 512 thr / 8 waves -------
// r17 winner + LDS atom-cache (cooperative per-edge atom load, 4x fewer gathers)
// + eidx prefetch at kernel top.
__global__ __launch_bounds__(512, 4) void k_edge(const float4* __restrict__ atoms5,
                                              const int*   __restrict__ eidx,
                                              const float* __restrict__ dnb,
                                              const int*   __restrict__ ridx,
                                              const int*   __restrict__ chl,
                                              const float* __restrict__ posW,
                                              const float* __restrict__ posb,
                                              const unsigned char* __restrict__ Wt,
                                              const float* __restrict__ lns,
                                              const float* __restrict__ lno,
                                              float* __restrict__ Eout)
{
    // LDS union: phase A: fA[64][424] = 27136 B + acache[64][10]f4 = 10240 B (37376)
    //            phase B: red[1024f] + red2[128f] + staging[64*132f] = 38400 B
    __shared__ __align__(16) unsigned char smem[38400];
    unsigned char (*fA)[FROW] = (unsigned char (*)[FROW])smem;
    float4* acache = (float4*)(smem + 27136);      // [64][10]
    int t = threadIdx.x;
    int base = blockIdx.x * BM;

    int w    = t >> 6;
    int lane = t & 63;
    int l16  = lane & 15;
    int lg   = lane >> 4;
    int g8   = lg * 8;
    int ncol = w * 16;

    // ---- prefetch edge metadata FIRST (L2 latency overlaps B preload + gi-side).
    int e0 = t >> 3;
    int q  = t & 7;
    int g  = base + e0;
    int j0 = eidx[g];                 // dependent chain head
    int gi = g / 30;                  // exact: g = b*61440 + i*30 + k
    int b_ = gi >> 11;

    // ---- B preload: 13 x 8B independent loads; latency hides under phase 1.
    const unsigned char* wtb = Wt + (size_t)(ncol + l16) * NEIN + g8;
    long bfr[13];
#pragma unroll
    for (int kt = 0; kt < 13; kt++)
        bfr[kt] = *(const long*)(wtb + kt * 32);

    // ---- phase 1: features, p-split, fp8-packed, exp2-domain RBF (raw v_exp).
    {
        int gj = (b_ << 11) + j0;

        // cooperative atom cache: slots 0-4 = A atoms, 5-9 = B atoms
        const float4* A4 = atoms5 + (size_t)gi * 5;
        const float4* B4 = atoms5 + (size_t)gj * 5;
        float4* ac = acache + e0 * 10;
        ac[q] = (q < 5) ? A4[q] : B4[q - 5];
        if (q < 2) ac[8 + q] = B4[3 + q];
        __builtin_amdgcn_wave_barrier();   // same-wave producers/consumers; fence compiler

        int off = ridx[gi] - ridx[gj];
        int ec  = (chl[gi] == chl[gj]) ? 1 : 0;
        int dp  = min(max(off + 32, 0), 64);
        dp = ec ? dp : 65;
        {
            float p0 = posW[dp * 16 + 2*q]     + posb[2*q];
            float p1 = posW[dp * 16 + 2*q + 1] + posb[2*q + 1];
            int r = __builtin_amdgcn_cvt_pk_fp8_f32(p0, p1, 0, false);
            *(unsigned short*)&fA[e0][q * 2] = (unsigned short)(r & 0xffff);
        }

        // exp(-(0.8(D-mu_s))^2) = 2^(-(a*D - a*mu_s)^2), a = 0.8*sqrt(log2 e)
        const float A_ = 0.96089792711f;
        const float C0 = 1.92179585422f;          // A_*2
        const float CS = 1.28119723615f;          // A_*(4/3)
        auto body = [&](int p) {
            float D;
            if (p == 0) {
                D = dnb[g];
            } else {
                float4 a  = ac[c_PA[p - 1]];
                float4 bb = ac[5 + c_PB[p - 1]];
                float dx = a.x - bb.x, dy = a.y - bb.y, dz = a.z - bb.z;
                D = __builtin_amdgcn_sqrtf(dx*dx + dy*dy + dz*dz + 1e-6f);
            }
            float aD = D * A_;
            int wds[4];
#pragma unroll
            for (int gq = 0; gq < 4; gq++) {
                float v[4];
#pragma unroll
                for (int u = 0; u < 4; u++) {
                    int s = gq * 4 + u;
                    float uu = aD - (C0 + (float)s * CS);
                    v[u] = __builtin_amdgcn_exp2f(-(uu * uu));   // raw v_exp_f32
                }
                int r = __builtin_amdgcn_cvt_pk_fp8_f32(v[0], v[1], 0, false);
                r = __builtin_amdgcn_cvt_pk_fp8_f32(v[2], v[3], r, true);
                wds[gq] = r;
            }
            long lo = ((long)(unsigned)wds[1] << 32) | (unsigned)wds[0];
            long hi = ((long)(unsigned)wds[3] << 32) | (unsigned)wds[2];
            *(long*)&fA[e0][16 + p * 16]     = lo;
            *(long*)&fA[e0][16 + p * 16 + 8] = hi;
        };

#pragma unroll
        for (int pp = 0; pp < 3; pp++) body(q + pp * 8);
        if (q == 0) body(24);
    }

    __syncthreads();                               // B1

    // ---- phase 2: GEMM. 52 MFMA + 52 conflict-free ds_read_b64 per wave.
    f32x4 acc[4];
#pragma unroll
    for (int mt = 0; mt < 4; mt++) acc[mt] = (f32x4){0.f, 0.f, 0.f, 0.f};

#pragma unroll
    for (int kt = 0; kt < 13; kt++) {
#pragma unroll
        for (int mt = 0; mt < 4; mt++) {
            long a = *(const long*)(&fA[mt * 16 + l16][kt * 32 + g8]);
            acc[mt] = __builtin_amdgcn_mfma_f32_16x16x32_fp8_fp8(a, bfr[kt], acc[mt], 0, 0, 0);
        }
    }

    // ---- phase 3: LayerNorm stats. 16-lane DPP reduce (VALU), combine via LDS.
    float sum[4][4], ssq[4][4];
#pragma unroll
    for (int mt = 0; mt < 4; mt++)
#pragma unroll
        for (int r = 0; r < 4; r++) {
            float v = acc[mt][r];
            sum[mt][r] = row16_sum(v);
            ssq[mt][r] = row16_sum(v * v);
        }

    __syncthreads();                               // B2: all fA reads done, reuse LDS
    float* red     = (float*)smem;                 // [64 rows][8 waves][2] = 4 KB
    float* red2    = red + 1024;                   // [64 rows][2] = 512 B
    float* staging = red2 + 128;                   // [64 rows][SROW] = 33792 B
    if (l16 == 0) {
#pragma unroll
        for (int mt = 0; mt < 4; mt++)
#pragma unroll
            for (int r = 0; r < 4; r++) {
                int row = mt * 16 + lg * 4 + r;
                red[(row * 8 + w) * 2 + 0] = sum[mt][r];
                red[(row * 8 + w) * 2 + 1] = ssq[mt][r];
            }
    }
    __syncthreads();                               // B3
    if (t < 64) {
        float ts = 0.f, tq = 0.f;
#pragma unroll
        for (int u = 0; u < 8; u++) {
            ts += red[(t * 8 + u) * 2 + 0];
            tq += red[(t * 8 + u) * 2 + 1];
        }
        float mu  = ts * (1.0f / 128.0f);
        float var = tq * (1.0f / 128.0f) - mu * mu;
        red2[t * 2 + 0] = mu;
        red2[t * 2 + 1] = 1.0f / sqrtf(var + 1e-5f);
    }
    __syncthreads();                               // B4

    // ---- phase 4: single staging pass (all 64 rows), NT stream LAST, no barrier after.
    float sc = lns[ncol + l16];
    float of = lno[ncol + l16];
#pragma unroll
    for (int mt = 0; mt < 4; mt++)
#pragma unroll
        for (int r = 0; r < 4; r++) {
            int row = mt * 16 + lg * 4 + r;
            float mu = red2[row * 2 + 0];
            float rs = red2[row * 2 + 1];
            staging[row * SROW + ncol + l16] =
                sc * ((acc[mt][r] - mu) * rs) + of;
        }
    __syncthreads();                               // B5

    f32x4* Eout4 = (f32x4*)Eout;
#pragma unroll
    for (int u = 0; u < 4; u++) {
        int idx  = u * 512 + t;                    // 0..2047
        int lrow = idx >> 5;
        int c4   = idx & 31;
        f32x4 val = *(f32x4*)&staging[lrow * SROW + c4 * 4];
        __builtin_nontemporal_store(val, &Eout4[(size_t)(base + lrow) * 32 + c4]);
    }
    // no trailing barrier: stores drain as waves retire
}

extern "C" void kernel_launch(void* const* d_in, const int* in_sizes, int n_in,
                              void* d_out, int out_size, void* d_ws, size_t ws_size,
                              hipStream_t stream)
{
    const float* X    = (const float*)d_in[0];
    const float* mask = (const float*)d_in[1];
    const int*   ridx = (const int*)d_in[2];
    const int*   chl  = (const int*)d_in[3];
    const float* posW = (const float*)d_in[4];
    const float* posb = (const float*)d_in[5];
    const float* eW   = (const float*)d_in[6];
    const float* lns  = (const float*)d_in[7];
    const float* lno  = (const float*)d_in[8];

    float* Eout   = (float*)d_out;                                  // B*L*K*128
    float* eidx_f = Eout + (size_t)NB * NL * NK * NEF;              // B*L*K (as float)

    char* ws = (char*)d_ws;
    float4*        atoms5 = (float4*)ws;                            // 327680 B
    float*         dnb    = (float*)(ws + 327680);                  // 491520 B
    int*           eidx   = (int*)(ws + 819200);                    // 491520 B
    unsigned char* Wt     = (unsigned char*)(ws + 1310720);         // 53248 B

    k_front<<<572, 512, 0, stream>>>(X, mask, eW, atoms5, Wt, dnb, eidx, eidx_f);
    k_edge<<<(NB * NL * NK) / BM, 512, 0, stream>>>(atoms5, eidx, dnb, ridx, chl,
                                                    posW, posb, Wt, lns, lno, Eout);
}

// Round 19
// 69.824 us; speedup vs baseline: 1.8463x; 1.0263x over previous
//
#include <hip/hip_runtime.h>
#include <math.h>

#define NB 2
#define NL 2048
#define NK 30
#define NEF 128
#define NEIN 416
#define BM 64            // edges per block in k_edge
#define FROW 424         // fA row stride (bytes): conflict-free quarter-wave b64 reads
#define SROW 132         // staging row stride (floats)

typedef float f32x4 __attribute__((ext_vector_type(4)));
typedef unsigned long long ull;

__constant__ int c_PA[24] = {0,2,3,4,1,1,1,1,0,0,0,4,4,3,0,2,3,4,2,3,4,2,3,2};
__constant__ int c_PB[24] = {0,2,3,4,0,2,3,4,2,3,4,2,3,2,1,1,1,1,0,0,0,4,4,3};

__device__ inline ull umin64(ull a, ull b) { return a < b ? a : b; }
__device__ inline ull umax64(ull a, ull b) { return a > b ? a : b; }

// ---- 16-lane f32 sum via DPP (VALU only). Bit-identical to shfl_xor 1,2,4,8.
template<int CTRL>
__device__ inline float dpp_add(float v) {
    int x = __builtin_amdgcn_update_dpp(0, __float_as_int(v), CTRL, 0xF, 0xF, true);
    return v + __int_as_float(x);
}
__device__ inline float row16_sum(float v) {
    v = dpp_add<0xB1>(v);    // quad_perm xor1
    v = dpp_add<0x4E>(v);    // quad_perm xor2
    v = dpp_add<0x141>(v);   // row_half_mirror == xor4
    v = dpp_add<0x140>(v);   // row_mirror      == xor8
    return v;
}

// ---- 64-lane u64 min: DPP for xor1..8, ds_swizzle for xor16, shfl for xor32.
template<int CTRL>
__device__ inline ull dpp_min64(ull v) {
    int lo = __builtin_amdgcn_update_dpp(0, (int)(unsigned)(v & 0xffffffffULL), CTRL, 0xF, 0xF, true);
    int hi = __builtin_amdgcn_update_dpp(0, (int)(unsigned)(v >> 32), CTRL, 0xF, 0xF, true);
    ull o = ((ull)(unsigned)hi << 32) | (unsigned)lo;
    return o < v ? o : v;
}
__device__ inline ull wave_min64(ull v) {
    v = dpp_min64<0xB1>(v);
    v = dpp_min64<0x4E>(v);
    v = dpp_min64<0x141>(v);
    v = dpp_min64<0x140>(v);
    {   // xor16 within each 32-lane half (BitMode: xor=16, and=0x1F)
        int lo = __builtin_amdgcn_ds_swizzle((int)(unsigned)(v & 0xffffffffULL), 0x401F);
        int hi = __builtin_amdgcn_ds_swizzle((int)(unsigned)(v >> 32), 0x401F);
        ull o = ((ull)(unsigned)hi << 32) | (unsigned)lo;
        v = o < v ? o : v;
    }
    {   // xor32
        int lo = __shfl_xor((int)(unsigned)(v & 0xffffffffULL), 32);
        int hi = __shfl_xor((int)(unsigned)(v >> 32), 32);
        ull o = ((ull)(unsigned)hi << 32) | (unsigned)lo;
        v = o < v ? o : v;
    }
    return v;
}

// ---- kernel 1 (merged front): blocks 0..511 = topk (coalesced float4 staging);
//      blocks 512..519 = atoms5 prep; blocks 520..571 = Wt fp8 prep.
__global__ __launch_bounds__(512, 4) void k_front(const float* __restrict__ X,
                                                  const float* __restrict__ mask,
                                                  const float* __restrict__ eW,
                                                  float4* __restrict__ atoms5,
                                                  unsigned char* __restrict__ Wt,
                                                  float* __restrict__ dnb,
                                                  int*   __restrict__ eidx,
                                                  float* __restrict__ eidx_f)
{
    __shared__ float4 ca[NL];
    int t = threadIdx.x;

    if (blockIdx.x >= 512) {
        if (blockIdx.x < 520) {
            // atoms5: [N,Ca,C,O,Cb] as 5x float4 per residue
            int idx = (blockIdx.x - 512) * 512 + t;       // 8*512 = 4096
            const float* x = X + (size_t)idx * 12;
            float N[3], Ca[3], C[3], O[3], bv[3], cv[3], av[3];
#pragma unroll
            for (int d = 0; d < 3; d++) { N[d] = x[d]; Ca[d] = x[3+d]; C[d] = x[6+d]; O[d] = x[9+d]; }
#pragma unroll
            for (int d = 0; d < 3; d++) { bv[d] = Ca[d] - N[d]; cv[d] = C[d] - Ca[d]; }
            av[0] = bv[1]*cv[2] - bv[2]*cv[1];
            av[1] = bv[2]*cv[0] - bv[0]*cv[2];
            av[2] = bv[0]*cv[1] - bv[1]*cv[0];
            float4* o = atoms5 + (size_t)idx * 5;
            o[0] = make_float4(N[0], N[1], N[2], 0.f);
            o[1] = make_float4(Ca[0], Ca[1], Ca[2], 0.f);
            o[2] = make_float4(C[0], C[1], C[2], 0.f);
            o[3] = make_float4(O[0], O[1], O[2], 0.f);
            float cb0 = -0.58273431f*av[0] + 0.56802827f*bv[0] - 0.54067466f*cv[0] + Ca[0];
            float cb1 = -0.58273431f*av[1] + 0.56802827f*bv[1] - 0.54067466f*cv[1] + Ca[1];
            float cb2 = -0.58273431f*av[2] + 0.56802827f*bv[2] - 0.54067466f*cv[2] + Ca[2];
            o[4] = make_float4(cb0, cb1, cb2, 0.f);
        } else {
            // Wt: W (416x128 f32) -> (128x416 fp8 e4m3)
            int idx = (blockIdx.x - 520) * 512 + t;       // 52*512 = 26624
            if (idx < NEF * (NEIN / 2)) {
                int c  = idx / (NEIN / 2);
                int k2 = idx - c * (NEIN / 2);
                float a = eW[(size_t)(2 * k2) * NEF + c];
                float b = eW[(size_t)(2 * k2 + 1) * NEF + c];
                int r = __builtin_amdgcn_cvt_pk_fp8_f32(a, b, 0, false);
                *(unsigned short*)&Wt[(size_t)c * NEIN + 2 * k2] = (unsigned short)(r & 0xffff);
            }
        }
        return;
    }

    // ---- topk: 8 rows per block, one wave per row; coalesced float4 staging.
    int base = blockIdx.x << 3;
    int b = base >> 11;
    const float4* X4 = (const float4*)(X + (size_t)b * NL * 12);   // 3 float4/residue
    const float* mb = mask + (size_t)b * NL;
#pragma unroll
    for (int r = 0; r < NL/512; r++) {
        int j = t + r * 512;
        float4 a0 = X4[(size_t)j * 3 + 0];   // N.xyz, Ca.x
        float4 a1 = X4[(size_t)j * 3 + 1];   // Ca.yz, C.xy
        ca[j] = make_float4(a0.w, a1.x, a1.y, mb[j]);
    }
    __syncthreads();

    int w = t >> 6, lane = t & 63;
    int row = base + w;
    int i = row & (NL - 1);
    float4 ci = ca[i];
    float mi = ci.w;

    float df[32];
    unsigned mflags = 0;
    float lmax = 0.0f;
#pragma unroll
    for (int r = 0; r < 32; r++) {
        float4 cj = ca[r*64 + lane];
        float dx = __fsub_rn(ci.x, cj.x);
        float dy = __fsub_rn(ci.y, cj.y);
        float dz = __fsub_rn(ci.z, cj.z);
        float s  = __fadd_rn(__fadd_rn(__fmul_rn(dx,dx), __fmul_rn(dy,dy)), __fmul_rn(dz,dz));
        s = __fadd_rn(s, 1e-6f);
        float m2 = __fmul_rn(mi, cj.w);   // binary mask: 0 or 1
        float d  = __fmul_rn(m2, __fsqrt_rn(s));
        df[r] = d;
        lmax = fmaxf(lmax, d);
        mflags |= (m2 != 0.0f) ? (1u << r) : 0u;
    }
#pragma unroll
    for (int off = 32; off; off >>= 1) lmax = fmaxf(lmax, __shfl_xor(lmax, off));
    unsigned rmb = __float_as_uint(lmax);

    const ull INF = ~0ULL;
    ull m0 = INF, m1 = INF, m2k = INF, m3 = INF;
#pragma unroll
    for (int r = 0; r < 32; r++) {
        unsigned hi = ((mflags >> r) & 1u) ? __float_as_uint(df[r]) : rmb;
        ull key = ((ull)hi << 32) | (unsigned)(r*64 + lane);
        ull a0 = umin64(key, m0); ull k1 = umax64(key, m0); m0 = a0;
        ull a1 = umin64(k1, m1);  ull k2 = umax64(k1, m1);  m1 = a1;
        ull a2 = umin64(k2, m2k); ull k3 = umax64(k2, m2k); m2k = a2;
        m3 = umin64(k3, m3);
    }

    int c = 0;
    ull mykey = 0;
    for (int sel = 0; sel < NK; sel++) {
        ull g = wave_min64(m0);
        if (m0 == g) {
            m0 = m1; m1 = m2k; m2k = m3; m3 = INF;
            c++;
            if (m0 == INF && c < 32) {
#pragma unroll
                for (int r = 0; r < 32; r++) {
                    unsigned hi = ((mflags >> r) & 1u) ? __float_as_uint(df[r]) : rmb;
                    ull key = ((ull)hi << 32) | (unsigned)(r*64 + lane);
                    if (key > g) {
                        ull a0 = umin64(key, m0); ull k1 = umax64(key, m0); m0 = a0;
                        ull a1 = umin64(k1, m1);  ull k2 = umax64(k1, m1);  m1 = a1;
                        ull a2 = umin64(k2, m2k); ull k3 = umax64(k2, m2k); m2k = a2;
                        m3 = umin64(k3, m3);
                    }
                }
            }
        }
        mykey = (lane == sel) ? g : mykey;
    }
    if (lane < NK) {
        int g = row * NK + lane;
        int j = (int)(mykey & 0xffffffffULL);
        dnb[g]    = __uint_as_float((unsigned)(mykey >> 32));
        eidx[g]   = j;
        eidx_f[g] = (float)j;
    }
}

// ------- kernel 2: features(fp8) + fp8 MFMA GEMM + LayerNorm, 512 thr / 8 waves -------
// RBF via geometric recurrence: f(s+1)=f(s)*r, r*=q -> 2 exps + 32 muls per p
// (was 16 exps). Drift <= 2e-6 rel, far below fp8 2^-4 quantization.
__global__ __launch_bounds__(512, 4) void k_edge(const float4* __restrict__ atoms5,
                                              const int*   __restrict__ eidx,
                                              const float* __restrict__ dnb,
                                              const int*   __restrict__ ridx,
                                              const int*   __restrict__ chl,
                                              const float* __restrict__ posW,
                                              const float* __restrict__ posb,
                                              const unsigned char* __restrict__ Wt,
                                              const float* __restrict__ lns,
                                              const float* __restrict__ lno,
                                              float* __restrict__ Eout)
{
    // LDS union: phase A: fA[64][424] = 27136 B + acache[64][10]f4 = 10240 B (37376)
    //            phase B: red[1024f] + red2[128f] + staging[64*132f] = 38400 B
    __shared__ __align__(16) unsigned char smem[38400];
    unsigned char (*fA)[FROW] = (unsigned char (*)[FROW])smem;
    float4* acache = (float4*)(smem + 27136);      // [64][10]
    int t = threadIdx.x;
    int base = blockIdx.x * BM;

    int w    = t >> 6;
    int lane = t & 63;
    int l16  = lane & 15;
    int lg   = lane >> 4;
    int g8   = lg * 8;
    int ncol = w * 16;

    // ---- prefetch edge metadata FIRST (L2 latency overlaps B preload).
    int e0 = t >> 3;
    int q  = t & 7;
    int g  = base + e0;
    int j0 = eidx[g];
    int gi = g / 30;                  // exact
    int b_ = gi >> 11;

    // ---- B preload: 13 x 8B independent loads; latency hides under phase 1.
    const unsigned char* wtb = Wt + (size_t)(ncol + l16) * NEIN + g8;
    long bfr[13];
#pragma unroll
    for (int kt = 0; kt < 13; kt++)
        bfr[kt] = *(const long*)(wtb + kt * 32);

    // ---- phase 1: features, p-split, fp8-packed, recurrence RBF.
    {
        int gj = (b_ << 11) + j0;

        const float4* A4 = atoms5 + (size_t)gi * 5;
        const float4* B4 = atoms5 + (size_t)gj * 5;
        float4* ac = acache + e0 * 10;
        ac[q] = (q < 5) ? A4[q] : B4[q - 5];
        if (q < 2) ac[8 + q] = B4[3 + q];
        __builtin_amdgcn_wave_barrier();

        int off = ridx[gi] - ridx[gj];
        int ec  = (chl[gi] == chl[gj]) ? 1 : 0;
        int dp  = min(max(off + 32, 0), 64);
        dp = ec ? dp : 65;
        {
            float p0 = posW[dp * 16 + 2*q]     + posb[2*q];
            float p1 = posW[dp * 16 + 2*q + 1] + posb[2*q + 1];
            int r = __builtin_amdgcn_cvt_pk_fp8_f32(p0, p1, 0, false);
            *(unsigned short*)&fA[e0][q * 2] = (unsigned short)(r & 0xffff);
        }

        // exp(-(0.8(D-mu_s))^2) = 2^(-(aD - c_s)^2); recurrence over s.
        const float A_ = 0.96089792711f;          // 0.8*sqrt(log2 e)
        const float C0 = 1.92179585422f;          // A_*2
        const float CS = 1.28119723615f;          // A_*(4/3)
        const float QQ = __builtin_amdgcn_exp2f(-2.0f * CS * CS);
        auto body = [&](int p) {
            float D;
            if (p == 0) {
                D = dnb[g];
            } else {
                float4 a  = ac[c_PA[p - 1]];
                float4 bb = ac[5 + c_PB[p - 1]];
                float dx = a.x - bb.x, dy = a.y - bb.y, dz = a.z - bb.z;
                D = __builtin_amdgcn_sqrtf(dx*dx + dy*dy + dz*dz + 1e-6f);
            }
            float u0 = D * A_ - C0;
            float f  = __builtin_amdgcn_exp2f(-(u0 * u0));
            float rr = __builtin_amdgcn_exp2f(CS * (2.0f * u0 - CS));
            int wds[4];
#pragma unroll
            for (int gq = 0; gq < 4; gq++) {
                float v[4];
#pragma unroll
                for (int u = 0; u < 4; u++) {
                    v[u] = f;
                    f  *= rr;
                    rr *= QQ;
                }
                int r = __builtin_amdgcn_cvt_pk_fp8_f32(v[0], v[1], 0, false);
                r = __builtin_amdgcn_cvt_pk_fp8_f32(v[2], v[3], r, true);
                wds[gq] = r;
            }
            long lo = ((long)(unsigned)wds[1] << 32) | (unsigned)wds[0];
            long hi = ((long)(unsigned)wds[3] << 32) | (unsigned)wds[2];
            *(long*)&fA[e0][16 + p * 16]     = lo;
            *(long*)&fA[e0][16 + p * 16 + 8] = hi;
        };

#pragma unroll
        for (int pp = 0; pp < 3; pp++) body(q + pp * 8);
        if (q == 0) body(24);
    }

    __syncthreads();                               // B1

    // ---- phase 2: GEMM. 52 MFMA + 52 conflict-free ds_read_b64 per wave.
    f32x4 acc[4];
#pragma unroll
    for (int mt = 0; mt < 4; mt++) acc[mt] = (f32x4){0.f, 0.f, 0.f, 0.f};

#pragma unroll
    for (int kt = 0; kt < 13; kt++) {
#pragma unroll
        for (int mt = 0; mt < 4; mt++) {
            long a = *(const long*)(&fA[mt * 16 + l16][kt * 32 + g8]);
            acc[mt] = __builtin_amdgcn_mfma_f32_16x16x32_fp8_fp8(a, bfr[kt], acc[mt], 0, 0, 0);
        }
    }

    // ---- phase 3: LayerNorm stats. 16-lane DPP reduce (VALU), combine via LDS.
    float sum[4][4], ssq[4][4];
#pragma unroll
    for (int mt = 0; mt < 4; mt++)
#pragma unroll
        for (int r = 0; r < 4; r++) {
            float v = acc[mt][r];
            sum[mt][r] = row16_sum(v);
            ssq[mt][r] = row16_sum(v * v);
        }

    __syncthreads();                               // B2: all fA reads done, reuse LDS
    float* red     = (float*)smem;                 // [64 rows][8 waves][2] = 4 KB
    float* red2    = red + 1024;                   // [64 rows][2] = 512 B
    float* staging = red2 + 128;                   // [64 rows][SROW] = 33792 B
    if (l16 == 0) {
#pragma unroll
        for (int mt = 0; mt < 4; mt++)
#pragma unroll
            for (int r = 0; r < 4; r++) {
                int row = mt * 16 + lg * 4 + r;
                red[(row * 8 + w) * 2 + 0] = sum[mt][r];
                red[(row * 8 + w) * 2 + 1] = ssq[mt][r];
            }
    }
    __syncthreads();                               // B3
    if (t < 64) {
        float ts = 0.f, tq = 0.f;
#pragma unroll
        for (int u = 0; u < 8; u++) {
            ts += red[(t * 8 + u) * 2 + 0];
            tq += red[(t * 8 + u) * 2 + 1];
        }
        float mu  = ts * (1.0f / 128.0f);
        float var = tq * (1.0f / 128.0f) - mu * mu;
        red2[t * 2 + 0] = mu;
        red2[t * 2 + 1] = 1.0f / sqrtf(var + 1e-5f);
    }
    __syncthreads();                               // B4

    // ---- phase 4: single staging pass (all 64 rows), NT stream LAST, no barrier after.
    float sc = lns[ncol + l16];
    float of = lno[ncol + l16];
#pragma unroll
    for (int mt = 0; mt < 4; mt++)
#pragma unroll
        for (int r = 0; r < 4; r++) {
            int row = mt * 16 + lg * 4 + r;
            float mu = red2[row * 2 + 0];
            float rs = red2[row * 2 + 1];
            staging[row * SROW + ncol + l16] =
                sc * ((acc[mt][r] - mu) * rs) + of;
        }
    __syncthreads();                               // B5

    f32x4* Eout4 = (f32x4*)Eout;
#pragma unroll
    for (int u = 0; u < 4; u++) {
        int idx  = u * 512 + t;                    // 0..2047
        int lrow = idx >> 5;
        int c4   = idx & 31;
        f32x4 val = *(f32x4*)&staging[lrow * SROW + c4 * 4];
        __builtin_nontemporal_store(val, &Eout4[(size_t)(base + lrow) * 32 + c4]);
    }
    // no trailing barrier: stores drain as waves retire
}

extern "C" void kernel_launch(void* const* d_in, const int* in_sizes, int n_in,
                              void* d_out, int out_size, void* d_ws, size_t ws_size,
                              hipStream_t stream)
{
    const float* X    = (const float*)d_in[0];
    const float* mask = (const float*)d_in[1];
    const int*   ridx = (const int*)d_in[2];
    const int*   chl  = (const int*)d_in[3];
    const float* posW = (const float*)d_in[4];
    const float* posb = (const float*)d_in[5];
    const float* eW   = (const float*)d_in[6];
    const float* lns  = (const float*)d_in[7];
    const float* lno  = (const float*)d_in[8];

    float* Eout   = (float*)d_out;                                  // B*L*K*128
    float* eidx_f = Eout + (size_t)NB * NL * NK * NEF;              // B*L*K (as float)

    char* ws = (char*)d_ws;
    float4*        atoms5 = (float4*)ws;                            // 327680 B
    float*         dnb    = (float*)(ws + 327680);                  // 491520 B
    int*           eidx   = (int*)(ws + 819200);                    // 491520 B
    unsigned char* Wt     = (unsigned char*)(ws + 1310720);         // 53248 B

    k_front<<<572, 512, 0, stream>>>(X, mask, eW, atoms5, Wt, dnb, eidx, eidx_f);
    k_edge<<<(NB * NL * NK) / BM, 512, 0, stream>>>(atoms5, eidx, dnb, ridx, chl,
                                                    posW, posb, Wt, lns, lno, Eout);
}